// Round 13
// baseline (777.689 us; speedup 1.0000x reference)
//
#include <hip/hip_runtime.h>
#include <stdint.h>

#define Ln 4
#define Bn 8
#define Sn 2048
#define Hn 1024
#define NHn 2
#define DHn 512
#define NSn 32
#define Mn (Bn*Sn)

typedef __attribute__((ext_vector_type(8))) short bf16x8;
typedef __attribute__((ext_vector_type(4))) float f32x4;
typedef unsigned short u16;

__device__ __forceinline__ float bf2f(u16 u){
  union { unsigned int i; float f; } c; c.i = ((unsigned int)u)<<16; return c.f;
}
__device__ __forceinline__ u16 f2bf(float f){
  union { float f; unsigned int i; } c; c.f = f;
  unsigned int r = c.i + 0x7FFFu + ((c.i>>16)&1u);
  return (u16)(r>>16);
}
__device__ __forceinline__ uint32_t packbf(float a, float b){
  return (uint32_t)f2bf(a) | ((uint32_t)f2bf(b)<<16);
}
__device__ __forceinline__ void gl2lds16(const void* g, void* l){
  __builtin_amdgcn_global_load_lds((const __attribute__((address_space(1))) void*)g,
                                   (__attribute__((address_space(3))) void*)l, 16, 0, 0);
}

__device__ __forceinline__ float block_sum256(float v, float* red){
#pragma unroll
  for (int m=32;m>=1;m>>=1) v += __shfl_xor(v, m, 64);
  int tid = threadIdx.x;
  if ((tid&63)==0) red[tid>>6] = v;
  __syncthreads();
  v = red[0]+red[1]+red[2]+red[3];
  __syncthreads();
  return v;
}

// ---------------- weight f32 -> bf16 ----------------
__global__ __launch_bounds__(256) void convw_kernel(const float* __restrict__ Wq, const float* __restrict__ Wk,
    const float* __restrict__ Wv, const float* __restrict__ Wo, u16* __restrict__ wb){
  int m = blockIdx.y;
  const float* src = (m==0)?Wq:(m==1)?Wk:(m==2)?Wv:Wo;
  size_t i = ((size_t)blockIdx.x*256 + threadIdx.x)*4;
  const float4 v = *(const float4*)&src[i];
  ushort4 o;
  o.x=f2bf(v.x); o.y=f2bf(v.y); o.z=f2bf(v.z); o.w=f2bf(v.w);
  *(ushort4*)&wb[(size_t)m*Hn*Hn + i] = o;
}

// ---------------- layer mix + LN1 -> x (bf16) ----------------
__global__ __launch_bounds__(256) void mixln_kernel(const float* __restrict__ hs, const float* __restrict__ lw,
    const float* __restrict__ g, const float* __restrict__ be, u16* __restrict__ xb){
  __shared__ float red[4];
  int row = blockIdx.x;
  int tid = threadIdx.x;
  float l0=lw[0], l1=lw[1], l2=lw[2], l3=lw[3];
  float mx = fmaxf(fmaxf(l0,l1),fmaxf(l2,l3));
  float e0=__expf(l0-mx), e1=__expf(l1-mx), e2=__expf(l2-mx), e3=__expf(l3-mx);
  float inv = 1.0f/(e0+e1+e2+e3);
  e0*=inv; e1*=inv; e2*=inv; e3*=inv;
  size_t base = (size_t)row*Hn + tid*4;
  const float4 h0 = *(const float4*)&hs[base];
  const float4 h1 = *(const float4*)&hs[base + (size_t)Mn*Hn];
  const float4 h2 = *(const float4*)&hs[base + (size_t)2*Mn*Hn];
  const float4 h3 = *(const float4*)&hs[base + (size_t)3*Mn*Hn];
  float x0 = e0*h0.x + e1*h1.x + e2*h2.x + e3*h3.x;
  float x1 = e0*h0.y + e1*h1.y + e2*h2.y + e3*h3.y;
  float x2 = e0*h0.z + e1*h1.z + e2*h2.z + e3*h3.z;
  float x3 = e0*h0.w + e1*h1.w + e2*h2.w + e3*h3.w;
  float s = block_sum256(x0+x1+x2+x3, red);
  float mean = s * (1.0f/Hn);
  float d0=x0-mean, d1=x1-mean, d2=x2-mean, d3=x3-mean;
  float sq = block_sum256(d0*d0+d1*d1+d2*d2+d3*d3, red);
  float rstd = rsqrtf(sq*(1.0f/Hn) + 1e-7f);
  int c = tid*4;
  ushort4 o;
  o.x = f2bf(d0*rstd*g[c+0] + be[c+0]);
  o.y = f2bf(d1*rstd*g[c+1] + be[c+1]);
  o.z = f2bf(d2*rstd*g[c+2] + be[c+2]);
  o.w = f2bf(d3*rstd*g[c+3] + be[c+3]);
  *(ushort4*)&xb[(size_t)row*Hn + c] = o;
}

// ---------------- GEMM 256x256, BK=64x2 per iter, 8-phase counted-vmcnt (R11, validated) ----------------
template<int MODE>
__global__ __launch_bounds__(512,2) void gemm256_kernel(const u16* __restrict__ A, const u16* __restrict__ Bw,
    const float* __restrict__ bias, const u16* __restrict__ resid, void* __restrict__ Cout, float scale){
  __shared__ char ldsb[131072];   // [buf][A/B][half][128x64 bf16 = 16KB]
  int tid = threadIdx.x, lane = tid&63, wid = tid>>6;
  int ln = lane&15, g4 = lane>>4;
  int wm = wid>>2, wn = wid&3;        // wave grid 2M x 4N; per-wave out 128x64
  int swz = (blockIdx.x&7)*32 + (blockIdx.x>>3);
  int i0 = (swz>>2)*256;
  int j0 = (swz&3)*256;

  f32x4 acc[8][4];
#pragma unroll
  for (int a=0;a<8;a++)
#pragma unroll
    for (int b=0;b<4;b++) acc[a][b] = (f32x4){0.f,0.f,0.f,0.f};

  const u16* Asrc = A + (size_t)i0*Hn;
  const u16* Bsrc = Bw + (size_t)j0*Hn;
  const int hA = wm, hB = wn>>1, bB = (wn&1)*64;

#define LDSOFF(B,AB,H) ((((B)*2+(AB))*2+(H))*16384)
#define STG(AB,H,B,T) do { \
    const u16* s_ = (AB) ? Bsrc : Asrc; \
    char* d_ = ldsb + LDSOFF(B,AB,H); \
    _Pragma("unroll") \
    for (int l_=0;l_<2;++l_){ \
      int g_ = l_*512 + tid; int r_ = g_>>3; int cs_ = (g_&7) ^ (r_&7); \
      gl2lds16(s_ + (size_t)((H)*128 + r_)*Hn + (T)*64 + cs_*8, d_ + g_*16); \
    } } while(0)
#define RDH(B,AB,H,RR,KG) (*(const bf16x8*)(ldsb + LDSOFF(B,AB,H) + (RR)*128 + ((((KG)) ^ ((RR)&7))<<4)))
#define LOADA(B,I) { _Pragma("unroll") for (int mt=0;mt<4;++mt) \
    _Pragma("unroll") for (int kk=0;kk<2;++kk) af[mt][kk] = RDH(B,0,hA,(I)*64+mt*16+ln, kk*4+g4); }
#define LOADB(B,ARR,J) { _Pragma("unroll") for (int nt=0;nt<2;++nt) \
    _Pragma("unroll") for (int kk=0;kk<2;++kk) ARR[nt][kk] = RDH(B,1,hB, bB+((J)*2+nt)*16+ln, kk*4+g4); }
#define PH_OPEN __builtin_amdgcn_s_barrier(); \
    asm volatile("s_waitcnt lgkmcnt(0)" ::: "memory"); \
    __builtin_amdgcn_sched_barrier(0);
#define MM(I,J,BF) { __builtin_amdgcn_s_setprio(1); \
    _Pragma("unroll") for (int kk=0;kk<2;++kk) \
    _Pragma("unroll") for (int mt=0;mt<4;++mt) \
    _Pragma("unroll") for (int nt=0;nt<2;++nt) \
      acc[(I)*4+mt][(J)*2+nt] = __builtin_amdgcn_mfma_f32_16x16x32_bf16(af[mt][kk], BF[nt][kk], acc[(I)*4+mt][(J)*2+nt], 0,0,0); \
    __builtin_amdgcn_s_setprio(0); }
#define PH_CLOSE __builtin_amdgcn_s_barrier();

  STG(0,0,0,0); STG(0,1,0,0); STG(1,0,0,0); STG(1,1,0,0);
  STG(0,0,1,1);
  asm volatile("s_waitcnt vmcnt(2)" ::: "memory");
  __builtin_amdgcn_s_barrier();

  bf16x8 af[4][2], bf0[2][2], bf1[2][2];
#pragma unroll 1
  for (int it=0; it<8; ++it){
    const int u = 2*it, v = 2*it+1;
    const bool st = (it < 7);
    LOADA(0,0); LOADB(0,bf0,0);
    STG(0,1,1,v);
    PH_OPEN; MM(0,0,bf0); PH_CLOSE;
    LOADB(0,bf1,1);
    STG(1,0,1,v);
    PH_OPEN; MM(0,1,bf1); PH_CLOSE;
    LOADA(0,1);
    STG(1,1,1,v);
    PH_OPEN; MM(1,0,bf0); PH_CLOSE;
    if (st) STG(0,0,0,u+2);
    PH_OPEN; MM(1,1,bf1);
    if (st) { asm volatile("s_waitcnt vmcnt(2)" ::: "memory"); }
    else    { asm volatile("s_waitcnt vmcnt(0)" ::: "memory"); }
    PH_CLOSE;
    LOADA(1,0); LOADB(1,bf0,0);
    if (st) STG(0,1,0,u+2);
    PH_OPEN; MM(0,0,bf0); PH_CLOSE;
    LOADB(1,bf1,1);
    if (st) STG(1,0,0,u+2);
    PH_OPEN; MM(0,1,bf1); PH_CLOSE;
    LOADA(1,1);
    if (st) STG(1,1,0,u+2);
    PH_OPEN; MM(1,0,bf0); PH_CLOSE;
    if (st) STG(0,0,1,v+2);
    PH_OPEN; MM(1,1,bf1);
    if (st) { asm volatile("s_waitcnt vmcnt(2)" ::: "memory"); }
    else    { asm volatile("s_waitcnt vmcnt(0)" ::: "memory"); }
    PH_CLOSE;
  }
#undef LDSOFF
#undef STG
#undef RDH
#undef LOADA
#undef LOADB
#undef PH_OPEN
#undef MM
#undef PH_CLOSE

#pragma unroll
  for (int mt=0; mt<8; ++mt){
#pragma unroll
    for (int nt=0; nt<4; ++nt){
#pragma unroll
      for (int r=0; r<4; ++r){
        int i = i0 + wm*128 + mt*16 + g4*4 + r;
        int j = j0 + wn*64 + nt*16 + ln;
        float v = acc[mt][nt][r] + bias[j];
        if (MODE==0){
          int b = i>>11, s = i&2047, nh = j>>9, dh = j&511;
          ((u16*)Cout)[(((size_t)(b*NHn+nh)*Sn + s)<<9) + dh] = f2bf(v*scale);
        } else if (MODE==1){
          int b = i>>11, s = i&2047, nh = j>>9, dh = j&511;
          ((u16*)Cout)[((size_t)((b*NHn+nh)*(Sn/32) + (s>>5))<<14) + (dh<<5) + (s&31)] = f2bf(v);
        } else {
          float res = bf2f(resid[(size_t)i*Hn + j]);
          ((u16*)Cout)[(size_t)i*Hn + j] = f2bf(v + res);
        }
      }
    }
  }
}

// ---------------- flash attention: 4-wave blocks, 2 independent blocks/CU ----------------
// 64 q/block, grid 512 (2 blocks/CU -> two independent barrier groups overlap stalls;
// same 8 waves/CU as R10). K,V single-buffered LDS (32KB each), alternating stage:
// stage V(kt) || QK -> sync -> stage K(kt+1) || PV -> sync. P block-shared 4KB.
// All swizzles identical to the validated R10 forms. LDS ~70KB/block.
__global__ __launch_bounds__(256,2) void attn_kernel(const u16* __restrict__ qb, const u16* __restrict__ kb,
    const u16* __restrict__ vt, const int* __restrict__ mask, u16* __restrict__ ctx){
  __shared__ u16 Ks[32*512];   // 32KB, row-swizzled
  __shared__ u16 Vs[512*32];   // 32KB, tiled V^T, granule-swizzled
  __shared__ u16 Ps[4*16*32];  // block-shared P[64q][32k], wave-region + granule-swizzled
  __shared__ float Lcorr[64];
  __shared__ float Lflag[4];
  __shared__ float Linv[64];
  int tid = threadIdx.x, lane = tid&63, wid = tid>>6;   // wid 0..3
  int ln = lane&15, g4 = lane>>4;
  int gid = blockIdx.x;
  int xcd = gid&7, ord = gid>>3;            // ord 0..63
  int bh = xcd*2 + (ord>>5), qt = ord&31;   // 32 qt-blocks of one bh share an XCD
  int b = bh >> 1, nh = bh & 1;
  u16* pw = Ps + wid*512;
  uint32_t* pw32 = (uint32_t*)pw;
  const int swz = (ln&7)<<4;
  const int rsw = (ln>>1)&3;     // P/V swizzle key

  bf16x8 aq[16];
  size_t qoff = ((size_t)bh*Sn + qt*64 + wid*16 + ln)*DHn + g4*8;
#pragma unroll
  for (int ch=0; ch<16; ++ch) aq[ch] = *(const bf16x8*)&qb[qoff + ch*32];

  // o2[qf][df]: q = qf*16 + g4*4 + r (qf 0..3); d = wid*128 + df*16 + ln (df 0..7)
  f32x4 o2[4][8];
#pragma unroll
  for (int qf=0; qf<4; ++qf)
#pragma unroll
    for (int df=0; df<8; ++df) o2[qf][df] = (f32x4){0.f,0.f,0.f,0.f};
  float mrun = -1e30f, lrun = 0.f;

  const size_t kbase = (size_t)bh*Sn*DHn;
  const u16* vtile = vt + (size_t)bh*Sn*DHn;   // tiled V^T: [kt][512 d][32 k]

#define STAGE_K32(KT) do { \
  _Pragma("unroll") \
  for (int t_=0; t_<8; ++t_){ \
    int krow_ = t_*4 + wid; \
    int koff_ = (lane*16) ^ ((krow_&7)<<4); \
    gl2lds16(&kb[kbase + ((size_t)((KT)*32 + krow_))*DHn + (koff_>>1)], \
             (char*)Ks + krow_*1024 + lane*16); \
  } } while(0)

#define STAGE_V32(KT) do { \
  _Pragma("unroll") \
  for (int t_=0; t_<8; ++t_){ \
    int p_ = t_*256 + tid; \
    int cgd_ = ((p_&3) ^ ((p_>>3)&3)); \
    gl2lds16(&vtile[(size_t)(KT)*16384 + (p_&~3)*8 + cgd_*8], \
             (char*)Vs + p_*16); \
  } } while(0)

  STAGE_K32(0);
  __syncthreads();   // K tile 0 resident
#pragma unroll 1
  for (int kt=0; kt<Sn/32; ++kt){
    STAGE_V32(kt);                       // V DMA overlaps QK
    const char* KsB = (const char*)Ks;
    f32x4 s0 = (f32x4){0.f,0.f,0.f,0.f};
    f32x4 s1 = (f32x4){0.f,0.f,0.f,0.f};
#pragma unroll
    for (int ch=0; ch<16; ++ch){
      int co = (ch*64 + g4*16) ^ swz;
      bf16x8 k0 = *(const bf16x8*)(KsB + ln*1024      + co);
      bf16x8 k1 = *(const bf16x8*)(KsB + (16+ln)*1024 + co);
      s0 = __builtin_amdgcn_mfma_f32_16x16x32_bf16(k0, aq[ch], s0, 0,0,0);
      s1 = __builtin_amdgcn_mfma_f32_16x16x32_bf16(k1, aq[ch], s1, 0,0,0);
    }
    int4 mk0 = *(const int4*)&mask[b*Sn + kt*32 + g4*4];
    int4 mk1 = *(const int4*)&mask[b*Sn + kt*32 + 16 + g4*4];
    s0[0] += (float)(1-mk0.x)*-10000.0f; s0[1] += (float)(1-mk0.y)*-10000.0f;
    s0[2] += (float)(1-mk0.z)*-10000.0f; s0[3] += (float)(1-mk0.w)*-10000.0f;
    s1[0] += (float)(1-mk1.x)*-10000.0f; s1[1] += (float)(1-mk1.y)*-10000.0f;
    s1[2] += (float)(1-mk1.z)*-10000.0f; s1[3] += (float)(1-mk1.w)*-10000.0f;
    float tmax = fmaxf(fmaxf(fmaxf(s0[0],s0[1]),fmaxf(s0[2],s0[3])),
                       fmaxf(fmaxf(s1[0],s1[1]),fmaxf(s1[2],s1[3])));
    tmax = fmaxf(tmax, __shfl_xor(tmax, 16));
    tmax = fmaxf(tmax, __shfl_xor(tmax, 32));
    float corr = 1.0f, wflag = 0.0f;
    if (__any(tmax > mrun + 8.0f)){     // defer-max: rare rescale
      float nm = fmaxf(mrun, tmax);
      corr = __expf(mrun - nm);
      mrun = nm; lrun *= corr;
      wflag = 1.0f;
    }
    float p0=__expf(s0[0]-mrun), p1=__expf(s0[1]-mrun), p2=__expf(s0[2]-mrun), p3=__expf(s0[3]-mrun);
    float p4=__expf(s1[0]-mrun), p5=__expf(s1[1]-mrun), p6=__expf(s1[2]-mrun), p7=__expf(s1[3]-mrun);
    float sum = ((p0+p1)+(p2+p3)) + ((p4+p5)+(p6+p7));
    sum += __shfl_xor(sum, 16);
    sum += __shfl_xor(sum, 32);
    lrun += sum;
    // P write: swizzled granules — granule (q,gr) at u16 q*32 + (gr^((q>>1)&3))*8.
    {
      int base = ln*16 + ((g4&1)<<1);
      pw32[base + (((g4>>1)    ^rsw)<<2)    ] = packbf(p0,p1);
      pw32[base + (((g4>>1)    ^rsw)<<2) + 1] = packbf(p2,p3);
      pw32[base + ((((g4>>1)+2)^rsw)<<2)    ] = packbf(p4,p5);
      pw32[base + ((((g4>>1)+2)^rsw)<<2) + 1] = packbf(p6,p7);
    }
    if (lane < 16) Lcorr[wid*16 + ln] = corr;
    if (lane == 0) Lflag[wid] = wflag;
    __syncthreads();                     // V landed (vmcnt0) + P visible; all K reads done
    if (kt < Sn/32 - 1) STAGE_K32(kt+1); // K DMA overlaps PV
    // cross-wave rescale (rare)
    {
      f32x4 fl = *(const f32x4*)&Lflag[0];
      float fs = (fl[0]+fl[1])+(fl[2]+fl[3]);
      if (fs > 0.5f){
#pragma unroll
        for (int qf=0; qf<4; ++qf){
          f32x4 c4 = *(const f32x4*)&Lcorr[qf*16 + g4*4];
#pragma unroll
          for (int df=0; df<8; ++df){
            o2[qf][df][0]*=c4[0]; o2[qf][df][1]*=c4[1];
            o2[qf][df][2]*=c4[2]; o2[qf][df][3]*=c4[3];
          }
        }
      }
    }
    // PV: wave computes all 64 q for its 128-wide d-slice; V from LDS
    const char* VsB = (const char*)Vs;
    bf16x8 bv[8];
#pragma unroll
    for (int df=0; df<8; ++df)
      bv[df] = *(const bf16x8*)(VsB + ((wid*8+df)*16+ln)*64 + ((g4 ^ rsw)<<4));
#pragma unroll
    for (int qf=0; qf<4; ++qf){
      bf16x8 aP = *(const bf16x8*)&Ps[qf*512 + ln*32 + ((g4 ^ rsw)<<3)];
#pragma unroll
      for (int df=0; df<8; ++df)
        o2[qf][df] = __builtin_amdgcn_mfma_f32_16x16x32_bf16(aP, bv[df], o2[qf][df], 0,0,0);
    }
    __syncthreads();                     // K(kt+1) landed; V region free for next stage
  }
#undef STAGE_K32
#undef STAGE_V32
  if (lane < 16) Linv[wid*16 + ln] = 1.0f/lrun;
  __syncthreads();
  int qr0 = qt*64;
#pragma unroll
  for (int qf=0; qf<4; ++qf){
    f32x4 il4 = *(const f32x4*)&Linv[qf*16 + g4*4];
#pragma unroll
    for (int df=0; df<8; ++df){
#pragma unroll
      for (int r=0; r<4; ++r){
        int q = qr0 + qf*16 + g4*4 + r;
        int d = nh*DHn + wid*128 + df*16 + ln;
        ctx[((size_t)(b*Sn + q))*Hn + d] = f2bf(o2[qf][df][r]*il4[r]);
      }
    }
  }
}

// ---------------- LN2 in-place on bf16 ----------------
__global__ __launch_bounds__(256) void ln2_kernel(u16* __restrict__ t, const float* __restrict__ g,
    const float* __restrict__ be){
  __shared__ float red[4];
  int row = blockIdx.x, tid = threadIdx.x;
  const ushort4 xu = *(const ushort4*)&t[(size_t)row*Hn + tid*4];
  float x0 = bf2f(xu.x), x1 = bf2f(xu.y), x2 = bf2f(xu.z), x3 = bf2f(xu.w);
  float s = block_sum256(x0+x1+x2+x3, red);
  float mean = s*(1.0f/Hn);
  float d0=x0-mean, d1=x1-mean, d2=x2-mean, d3=x3-mean;
  float sq = block_sum256(d0*d0+d1*d1+d2*d2+d3*d3, red);
  float rstd = rsqrtf(sq*(1.0f/Hn) + 1e-12f);
  int c = tid*4;
  ushort4 y;
  y.x = f2bf(d0*rstd*g[c+0] + be[c+0]);
  y.y = f2bf(d1*rstd*g[c+1] + be[c+1]);
  y.z = f2bf(d2*rstd*g[c+2] + be[c+2]);
  y.w = f2bf(d3*rstd*g[c+3] + be[c+3]);
  *(ushort4*)&t[(size_t)row*Hn + c] = y;
}

// ---------------- span mean (bf16 input) ----------------
__global__ __launch_bounds__(256) void span_kernel(const u16* __restrict__ y, const int* __restrict__ head,
    const int* __restrict__ tail, float* __restrict__ out){
  int bs = blockIdx.x;
  int b = bs >> 5;
  int hd = head[bs], tl = tail[bs];
  int c = threadIdx.x*4;
  float a0=0.f,a1=0.f,a2=0.f,a3=0.f;
  for (int s=hd; s<tl; ++s){
    const ushort4 v = *(const ushort4*)&y[((size_t)(b*Sn + s))*Hn + c];
    a0+=bf2f(v.x); a1+=bf2f(v.y); a2+=bf2f(v.z); a3+=bf2f(v.w);
  }
  float inv = 1.0f/(float)(tl-hd);
  float4 o; o.x=a0*inv; o.y=a1*inv; o.z=a2*inv; o.w=a3*inv;
  *(float4*)&out[(size_t)bs*Hn + c] = o;
}

extern "C" void kernel_launch(void* const* d_in, const int* in_sizes, int n_in,
                              void* d_out, int out_size, void* d_ws, size_t ws_size,
                              hipStream_t stream) {
  const float* hs    = (const float*)d_in[0];
  const int*   mask  = (const int*)d_in[1];
  const int*   shead = (const int*)d_in[2];
  const int*   stail = (const int*)d_in[3];
  const float* lw    = (const float*)d_in[4];
  const float* ln1g  = (const float*)d_in[5];
  const float* ln1b  = (const float*)d_in[6];
  const float* Wq    = (const float*)d_in[7];
  const float* bq    = (const float*)d_in[8];
  const float* Wk    = (const float*)d_in[9];
  const float* bk    = (const float*)d_in[10];
  const float* Wv    = (const float*)d_in[11];
  const float* bv    = (const float*)d_in[12];
  const float* Wo    = (const float*)d_in[13];
  const float* bo    = (const float*)d_in[14];
  const float* ln2g  = (const float*)d_in[15];
  const float* ln2b  = (const float*)d_in[16];

  char* ws = (char*)d_ws;
  u16* xb  = (u16*)(ws);                 // 32 MiB
  u16* wb  = (u16*)(ws + 33554432);      // 8 MiB (Wq,Wk,Wv,Wo bf16)
  u16* qb  = (u16*)(ws + 41943040);      // 32 MiB
  u16* kb  = (u16*)(ws + 75497472);      // 32 MiB
  u16* vt  = (u16*)(ws + 109051904);     // 32 MiB
  u16* ctx = (u16*)(ws + 142606336);     // 32 MiB ; ends at 176160768
  u16* t   = (u16*)(ws + 41943040);      // 32 MiB bf16, overlays qb (dead after attn)
  float* out = (float*)d_out;

  convw_kernel<<<dim3(1024,4),256,0,stream>>>(Wq,Wk,Wv,Wo,wb);
  mixln_kernel<<<Mn,256,0,stream>>>(hs,lw,ln1g,ln1b,xb);
  gemm256_kernel<0><<<256,512,0,stream>>>(xb, wb,           bq, nullptr, qb, 0.044194173824159223f);
  gemm256_kernel<0><<<256,512,0,stream>>>(xb, wb+1048576,   bk, nullptr, kb, 1.0f);
  gemm256_kernel<1><<<256,512,0,stream>>>(xb, wb+2097152,   bv, nullptr, vt, 1.0f);
  attn_kernel<<<512,256,0,stream>>>(qb,kb,vt,mask,ctx);
  gemm256_kernel<2><<<256,512,0,stream>>>(ctx, wb+3145728,  bo, xb, t, 1.0f);
  ln2_kernel<<<Mn,256,0,stream>>>(t, ln2g, ln2b);
  span_kernel<<<Bn*NSn,256,0,stream>>>(t, shead, stail, out);
}

// Round 14
// 577.986 us; speedup vs baseline: 1.3455x; 1.3455x over previous
//
#include <hip/hip_runtime.h>
#include <stdint.h>

#define Ln 4
#define Bn 8
#define Sn 2048
#define Hn 1024
#define NHn 2
#define DHn 512
#define NSn 32
#define Mn (Bn*Sn)

typedef __attribute__((ext_vector_type(8))) short bf16x8;
typedef __attribute__((ext_vector_type(4))) float f32x4;
typedef unsigned short u16;

__device__ __forceinline__ float bf2f(u16 u){
  union { unsigned int i; float f; } c; c.i = ((unsigned int)u)<<16; return c.f;
}
__device__ __forceinline__ u16 f2bf(float f){
  union { float f; unsigned int i; } c; c.f = f;
  unsigned int r = c.i + 0x7FFFu + ((c.i>>16)&1u);
  return (u16)(r>>16);
}
__device__ __forceinline__ uint32_t packbf(float a, float b){
  return (uint32_t)f2bf(a) | ((uint32_t)f2bf(b)<<16);
}
__device__ __forceinline__ void gl2lds16(const void* g, void* l){
  __builtin_amdgcn_global_load_lds((const __attribute__((address_space(1))) void*)g,
                                   (__attribute__((address_space(3))) void*)l, 16, 0, 0);
}

__device__ __forceinline__ float block_sum256(float v, float* red){
#pragma unroll
  for (int m=32;m>=1;m>>=1) v += __shfl_xor(v, m, 64);
  int tid = threadIdx.x;
  if ((tid&63)==0) red[tid>>6] = v;
  __syncthreads();
  v = red[0]+red[1]+red[2]+red[3];
  __syncthreads();
  return v;
}

// ---------------- weight f32 -> bf16 ----------------
__global__ __launch_bounds__(256) void convw_kernel(const float* __restrict__ Wq, const float* __restrict__ Wk,
    const float* __restrict__ Wv, const float* __restrict__ Wo, u16* __restrict__ wb){
  int m = blockIdx.y;
  const float* src = (m==0)?Wq:(m==1)?Wk:(m==2)?Wv:Wo;
  size_t i = ((size_t)blockIdx.x*256 + threadIdx.x)*4;
  const float4 v = *(const float4*)&src[i];
  ushort4 o;
  o.x=f2bf(v.x); o.y=f2bf(v.y); o.z=f2bf(v.z); o.w=f2bf(v.w);
  *(ushort4*)&wb[(size_t)m*Hn*Hn + i] = o;
}

// ---------------- layer mix + LN1 -> x (bf16) ----------------
__global__ __launch_bounds__(256) void mixln_kernel(const float* __restrict__ hs, const float* __restrict__ lw,
    const float* __restrict__ g, const float* __restrict__ be, u16* __restrict__ xb){
  __shared__ float red[4];
  int row = blockIdx.x;
  int tid = threadIdx.x;
  float l0=lw[0], l1=lw[1], l2=lw[2], l3=lw[3];
  float mx = fmaxf(fmaxf(l0,l1),fmaxf(l2,l3));
  float e0=__expf(l0-mx), e1=__expf(l1-mx), e2=__expf(l2-mx), e3=__expf(l3-mx);
  float inv = 1.0f/(e0+e1+e2+e3);
  e0*=inv; e1*=inv; e2*=inv; e3*=inv;
  size_t base = (size_t)row*Hn + tid*4;
  const float4 h0 = *(const float4*)&hs[base];
  const float4 h1 = *(const float4*)&hs[base + (size_t)Mn*Hn];
  const float4 h2 = *(const float4*)&hs[base + (size_t)2*Mn*Hn];
  const float4 h3 = *(const float4*)&hs[base + (size_t)3*Mn*Hn];
  float x0 = e0*h0.x + e1*h1.x + e2*h2.x + e3*h3.x;
  float x1 = e0*h0.y + e1*h1.y + e2*h2.y + e3*h3.y;
  float x2 = e0*h0.z + e1*h1.z + e2*h2.z + e3*h3.z;
  float x3 = e0*h0.w + e1*h1.w + e2*h2.w + e3*h3.w;
  float s = block_sum256(x0+x1+x2+x3, red);
  float mean = s * (1.0f/Hn);
  float d0=x0-mean, d1=x1-mean, d2=x2-mean, d3=x3-mean;
  float sq = block_sum256(d0*d0+d1*d1+d2*d2+d3*d3, red);
  float rstd = rsqrtf(sq*(1.0f/Hn) + 1e-7f);
  int c = tid*4;
  ushort4 o;
  o.x = f2bf(d0*rstd*g[c+0] + be[c+0]);
  o.y = f2bf(d1*rstd*g[c+1] + be[c+1]);
  o.z = f2bf(d2*rstd*g[c+2] + be[c+2]);
  o.w = f2bf(d3*rstd*g[c+3] + be[c+3]);
  *(ushort4*)&xb[(size_t)row*Hn + c] = o;
}

// ---------------- GEMM 256x256, BK=64x2 per iter, 8-phase counted-vmcnt (R11, validated) ----------------
template<int MODE>
__global__ __launch_bounds__(512,2) void gemm256_kernel(const u16* __restrict__ A, const u16* __restrict__ Bw,
    const float* __restrict__ bias, const u16* __restrict__ resid, void* __restrict__ Cout, float scale){
  __shared__ char ldsb[131072];   // [buf][A/B][half][128x64 bf16 = 16KB]
  int tid = threadIdx.x, lane = tid&63, wid = tid>>6;
  int ln = lane&15, g4 = lane>>4;
  int wm = wid>>2, wn = wid&3;        // wave grid 2M x 4N; per-wave out 128x64
  int swz = (blockIdx.x&7)*32 + (blockIdx.x>>3);
  int i0 = (swz>>2)*256;
  int j0 = (swz&3)*256;

  f32x4 acc[8][4];
#pragma unroll
  for (int a=0;a<8;a++)
#pragma unroll
    for (int b=0;b<4;b++) acc[a][b] = (f32x4){0.f,0.f,0.f,0.f};

  const u16* Asrc = A + (size_t)i0*Hn;
  const u16* Bsrc = Bw + (size_t)j0*Hn;
  const int hA = wm, hB = wn>>1, bB = (wn&1)*64;

#define LDSOFF(B,AB,H) ((((B)*2+(AB))*2+(H))*16384)
#define STG(AB,H,B,T) do { \
    const u16* s_ = (AB) ? Bsrc : Asrc; \
    char* d_ = ldsb + LDSOFF(B,AB,H); \
    _Pragma("unroll") \
    for (int l_=0;l_<2;++l_){ \
      int g_ = l_*512 + tid; int r_ = g_>>3; int cs_ = (g_&7) ^ (r_&7); \
      gl2lds16(s_ + (size_t)((H)*128 + r_)*Hn + (T)*64 + cs_*8, d_ + g_*16); \
    } } while(0)
#define RDH(B,AB,H,RR,KG) (*(const bf16x8*)(ldsb + LDSOFF(B,AB,H) + (RR)*128 + ((((KG)) ^ ((RR)&7))<<4)))
#define LOADA(B,I) { _Pragma("unroll") for (int mt=0;mt<4;++mt) \
    _Pragma("unroll") for (int kk=0;kk<2;++kk) af[mt][kk] = RDH(B,0,hA,(I)*64+mt*16+ln, kk*4+g4); }
#define LOADB(B,ARR,J) { _Pragma("unroll") for (int nt=0;nt<2;++nt) \
    _Pragma("unroll") for (int kk=0;kk<2;++kk) ARR[nt][kk] = RDH(B,1,hB, bB+((J)*2+nt)*16+ln, kk*4+g4); }
#define PH_OPEN __builtin_amdgcn_s_barrier(); \
    asm volatile("s_waitcnt lgkmcnt(0)" ::: "memory"); \
    __builtin_amdgcn_sched_barrier(0);
#define MM(I,J,BF) { __builtin_amdgcn_s_setprio(1); \
    _Pragma("unroll") for (int kk=0;kk<2;++kk) \
    _Pragma("unroll") for (int mt=0;mt<4;++mt) \
    _Pragma("unroll") for (int nt=0;nt<2;++nt) \
      acc[(I)*4+mt][(J)*2+nt] = __builtin_amdgcn_mfma_f32_16x16x32_bf16(af[mt][kk], BF[nt][kk], acc[(I)*4+mt][(J)*2+nt], 0,0,0); \
    __builtin_amdgcn_s_setprio(0); }
#define PH_CLOSE __builtin_amdgcn_s_barrier();

  STG(0,0,0,0); STG(0,1,0,0); STG(1,0,0,0); STG(1,1,0,0);
  STG(0,0,1,1);
  asm volatile("s_waitcnt vmcnt(2)" ::: "memory");
  __builtin_amdgcn_s_barrier();

  bf16x8 af[4][2], bf0[2][2], bf1[2][2];
#pragma unroll 1
  for (int it=0; it<8; ++it){
    const int u = 2*it, v = 2*it+1;
    const bool st = (it < 7);
    LOADA(0,0); LOADB(0,bf0,0);
    STG(0,1,1,v);
    PH_OPEN; MM(0,0,bf0); PH_CLOSE;
    LOADB(0,bf1,1);
    STG(1,0,1,v);
    PH_OPEN; MM(0,1,bf1); PH_CLOSE;
    LOADA(0,1);
    STG(1,1,1,v);
    PH_OPEN; MM(1,0,bf0); PH_CLOSE;
    if (st) STG(0,0,0,u+2);
    PH_OPEN; MM(1,1,bf1);
    if (st) { asm volatile("s_waitcnt vmcnt(2)" ::: "memory"); }
    else    { asm volatile("s_waitcnt vmcnt(0)" ::: "memory"); }
    PH_CLOSE;
    LOADA(1,0); LOADB(1,bf0,0);
    if (st) STG(0,1,0,u+2);
    PH_OPEN; MM(0,0,bf0); PH_CLOSE;
    LOADB(1,bf1,1);
    if (st) STG(1,0,0,u+2);
    PH_OPEN; MM(0,1,bf1); PH_CLOSE;
    LOADA(1,1);
    if (st) STG(1,1,0,u+2);
    PH_OPEN; MM(1,0,bf0); PH_CLOSE;
    if (st) STG(0,0,1,v+2);
    PH_OPEN; MM(1,1,bf1);
    if (st) { asm volatile("s_waitcnt vmcnt(2)" ::: "memory"); }
    else    { asm volatile("s_waitcnt vmcnt(0)" ::: "memory"); }
    PH_CLOSE;
  }
#undef LDSOFF
#undef STG
#undef RDH
#undef LOADA
#undef LOADB
#undef PH_OPEN
#undef MM
#undef PH_CLOSE

#pragma unroll
  for (int mt=0; mt<8; ++mt){
#pragma unroll
    for (int nt=0; nt<4; ++nt){
#pragma unroll
      for (int r=0; r<4; ++r){
        int i = i0 + wm*128 + mt*16 + g4*4 + r;
        int j = j0 + wn*64 + nt*16 + ln;
        float v = acc[mt][nt][r] + bias[j];
        if (MODE==0){
          int b = i>>11, s = i&2047, nh = j>>9, dh = j&511;
          ((u16*)Cout)[(((size_t)(b*NHn+nh)*Sn + s)<<9) + dh] = f2bf(v*scale);
        } else if (MODE==1){
          int b = i>>11, s = i&2047, nh = j>>9, dh = j&511;
          ((u16*)Cout)[((size_t)((b*NHn+nh)*(Sn/32) + (s>>5))<<14) + (dh<<5) + (s&31)] = f2bf(v);
        } else {
          float res = bf2f(resid[(size_t)i*Hn + j]);
          ((u16*)Cout)[(size_t)i*Hn + j] = f2bf(v + res);
        }
      }
    }
  }
}

// ---------------- flash attention: lagged-PV single-barrier pipeline ----------------
// R10 structure (8 waves, 128q, d-split PV, K+V dbuf) but PV runs ONE TILE BEHIND
// QK: per iter {stage K(kt+1)->Ks[pb], V(kt)->Vs[cur] || QK(kt) -> softmax ->
// P(kt)->Ps[cur] -> rescale(corr(kt-1)) + PV(kt-1) from Ps[pb]/Vs[pb]} -> ONE
// syncthreads. End barrier gives P visibility + DMA drain + buffer rotation.
// Disjointness/iter: writes {Ks[pb],Vs[cur],Ps[cur]}, reads {Ks[cur],Vs[pb],Ps[pb]}.
// Epilogue flushes PV(63). Compiler free to interleave PV MFMAs with softmax VALU.
__global__ __launch_bounds__(512,2) void attn_kernel(const u16* __restrict__ qb, const u16* __restrict__ kb,
    const u16* __restrict__ vt, const int* __restrict__ mask, u16* __restrict__ ctx){
  __shared__ u16 Ks[2][32*512];   // 64KB, row-swizzled
  __shared__ u16 Vs[2][512*32];   // 64KB, tiled V^T, granule-swizzled
  __shared__ u16 Ps[2][8*16*32];  // 16KB, double-buffered block-shared P
  __shared__ float Lcorr[2][128];
  __shared__ float Lflag[2][8];
  __shared__ float Linv[128];
  int tid = threadIdx.x, lane = tid&63, wid = tid>>6;
  int ln = lane&15, g4 = lane>>4;
  int gid = blockIdx.x;
  int xcd = gid&7, ord = gid>>3;
  int bh = xcd*2 + (ord>>4), qt = ord&15;   // 16 qt-blocks of one bh share an XCD
  int b = bh >> 1, nh = bh & 1;
  const int swz = (ln&7)<<4;
  const int rsw = (ln>>1)&3;     // P/V swizzle key

  bf16x8 aq[16];
  size_t qoff = ((size_t)bh*Sn + qt*128 + wid*16 + ln)*DHn + g4*8;
#pragma unroll
  for (int ch=0; ch<16; ++ch) aq[ch] = *(const bf16x8*)&qb[qoff + ch*32];

  // o2[qf][df]: q = qf*16 + g4*4 + r ; d = wid*64 + df*16 + ln
  f32x4 o2[8][4];
#pragma unroll
  for (int qf=0; qf<8; ++qf)
#pragma unroll
    for (int df=0; df<4; ++df) o2[qf][df] = (f32x4){0.f,0.f,0.f,0.f};
  float mrun = -1e30f, lrun = 0.f;

  const size_t kbase = (size_t)bh*Sn*DHn;
  const u16* vtile = vt + (size_t)bh*Sn*DHn;   // tiled V^T: [kt][512 d][32 k]

#define STAGE_K(KT,BUF) do { \
  _Pragma("unroll") \
  for (int t_=0; t_<4; ++t_){ \
    int krow_ = t_*8 + wid; \
    int koff_ = (lane*16) ^ ((krow_&7)<<4); \
    gl2lds16(&kb[kbase + ((size_t)((KT)*32 + krow_))*DHn + (koff_>>1)], \
             (char*)Ks[BUF] + krow_*1024 + lane*16); \
  } } while(0)

#define STAGE_V(KT,BUF) do { \
  _Pragma("unroll") \
  for (int t_=0; t_<4; ++t_){ \
    int p_ = t_*512 + tid; \
    int cgd_ = ((p_&3) ^ ((p_>>3)&3)); \
    gl2lds16(&vtile[(size_t)(KT)*16384 + (p_&~3)*8 + cgd_*8], \
             (char*)Vs[BUF] + p_*16); \
  } } while(0)

#define DO_PV(PB) do { \
    f32x4 fl0 = *(const f32x4*)&Lflag[PB][0]; \
    f32x4 fl1 = *(const f32x4*)&Lflag[PB][4]; \
    float fs = (fl0[0]+fl0[1]+fl0[2]+fl0[3]) + (fl1[0]+fl1[1]+fl1[2]+fl1[3]); \
    if (fs > 0.5f){ \
      _Pragma("unroll") \
      for (int qf=0; qf<8; ++qf){ \
        f32x4 c4 = *(const f32x4*)&Lcorr[PB][qf*16 + g4*4]; \
        _Pragma("unroll") \
        for (int df=0; df<4; ++df){ \
          o2[qf][df][0]*=c4[0]; o2[qf][df][1]*=c4[1]; \
          o2[qf][df][2]*=c4[2]; o2[qf][df][3]*=c4[3]; \
        } \
      } \
    } \
    const char* VsB = (const char*)Vs[PB]; \
    bf16x8 bv[4]; \
    _Pragma("unroll") \
    for (int df=0; df<4; ++df) \
      bv[df] = *(const bf16x8*)(VsB + ((wid*4+df)*16+ln)*64 + ((g4 ^ rsw)<<4)); \
    _Pragma("unroll") \
    for (int qf=0; qf<8; ++qf){ \
      bf16x8 aP = *(const bf16x8*)&Ps[PB][qf*512 + ln*32 + ((g4 ^ rsw)<<3)]; \
      _Pragma("unroll") \
      for (int df=0; df<4; ++df) \
        o2[qf][df] = __builtin_amdgcn_mfma_f32_16x16x32_bf16(aP, bv[df], o2[qf][df], 0,0,0); \
    } } while(0)

  STAGE_K(0,0);
  __syncthreads();   // K(0) resident
#pragma unroll 1
  for (int kt=0; kt<Sn/32; ++kt){
    int cur = kt&1, pb = cur^1;
    if (kt < Sn/32 - 1) STAGE_K(kt+1, pb);   // K(kt+1); Ks[pb] held K(kt-1), reads done
    STAGE_V(kt, cur);                        // V(kt); consumed next iter as pb
    const char* KsB = (const char*)Ks[cur];
    f32x4 s0 = (f32x4){0.f,0.f,0.f,0.f};
    f32x4 s1 = (f32x4){0.f,0.f,0.f,0.f};
#pragma unroll
    for (int ch=0; ch<16; ++ch){
      bf16x8 k0 = *(const bf16x8*)(KsB + ln*1024      + ((ch*64 + g4*16) ^ swz));
      bf16x8 k1 = *(const bf16x8*)(KsB + (16+ln)*1024 + ((ch*64 + g4*16) ^ swz));
      s0 = __builtin_amdgcn_mfma_f32_16x16x32_bf16(k0, aq[ch], s0, 0,0,0);
      s1 = __builtin_amdgcn_mfma_f32_16x16x32_bf16(k1, aq[ch], s1, 0,0,0);
    }
    int4 mk0 = *(const int4*)&mask[b*Sn + kt*32 + g4*4];
    int4 mk1 = *(const int4*)&mask[b*Sn + kt*32 + 16 + g4*4];
    s0[0] += (float)(1-mk0.x)*-10000.0f; s0[1] += (float)(1-mk0.y)*-10000.0f;
    s0[2] += (float)(1-mk0.z)*-10000.0f; s0[3] += (float)(1-mk0.w)*-10000.0f;
    s1[0] += (float)(1-mk1.x)*-10000.0f; s1[1] += (float)(1-mk1.y)*-10000.0f;
    s1[2] += (float)(1-mk1.z)*-10000.0f; s1[3] += (float)(1-mk1.w)*-10000.0f;
    float tmax = fmaxf(fmaxf(fmaxf(s0[0],s0[1]),fmaxf(s0[2],s0[3])),
                       fmaxf(fmaxf(s1[0],s1[1]),fmaxf(s1[2],s1[3])));
    tmax = fmaxf(tmax, __shfl_xor(tmax, 16));
    tmax = fmaxf(tmax, __shfl_xor(tmax, 32));
    float corr = 1.0f, wflag = 0.0f;
    if (__any(tmax > mrun + 8.0f)){     // defer-max: rare rescale
      float nm = fmaxf(mrun, tmax);
      corr = __expf(mrun - nm);
      mrun = nm; lrun *= corr;
      wflag = 1.0f;
    }
    float p0=__expf(s0[0]-mrun), p1=__expf(s0[1]-mrun), p2=__expf(s0[2]-mrun), p3=__expf(s0[3]-mrun);
    float p4=__expf(s1[0]-mrun), p5=__expf(s1[1]-mrun), p6=__expf(s1[2]-mrun), p7=__expf(s1[3]-mrun);
    float sum = ((p0+p1)+(p2+p3)) + ((p4+p5)+(p6+p7));
    sum += __shfl_xor(sum, 16);
    sum += __shfl_xor(sum, 32);
    lrun += sum;
    // P(kt) write into Ps[cur] (wave-private region; consumed next iter cross-wave)
    {
      uint32_t* pw32 = (uint32_t*)(Ps[cur] + wid*512);
      int base = ln*16 + ((g4&1)<<1);
      pw32[base + (((g4>>1)    ^rsw)<<2)    ] = packbf(p0,p1);
      pw32[base + (((g4>>1)    ^rsw)<<2) + 1] = packbf(p2,p3);
      pw32[base + ((((g4>>1)+2)^rsw)<<2)    ] = packbf(p4,p5);
      pw32[base + ((((g4>>1)+2)^rsw)<<2) + 1] = packbf(p6,p7);
    }
    if (lane < 16) Lcorr[cur][wid*16 + ln] = corr;
    if (lane == 0) Lflag[cur][wid] = wflag;
    // ---- PV of PREVIOUS tile (kt-1) from Ps[pb]/Vs[pb]/Lcorr[pb]
    if (kt > 0) DO_PV(pb);
    __syncthreads();   // drains DMA (K(kt+1),V(kt)); makes P(kt)/Lcorr(kt) visible
  }
  // epilogue: flush PV(63) — P/V/corr in buffer (63&1)=1, made visible by last barrier
  DO_PV(1);
#undef STAGE_K
#undef STAGE_V
#undef DO_PV
  if (lane < 16) Linv[wid*16 + ln] = 1.0f/lrun;
  __syncthreads();
  int qr0 = qt*128;
#pragma unroll
  for (int qf=0; qf<8; ++qf){
    f32x4 il4 = *(const f32x4*)&Linv[qf*16 + g4*4];
#pragma unroll
    for (int df=0; df<4; ++df){
#pragma unroll
      for (int r=0; r<4; ++r){
        int q = qr0 + qf*16 + g4*4 + r;
        int d = nh*DHn + wid*64 + df*16 + ln;
        ctx[((size_t)(b*Sn + q))*Hn + d] = f2bf(o2[qf][df][r]*il4[r]);
      }
    }
  }
}

// ---------------- LN2 in-place on bf16 ----------------
__global__ __launch_bounds__(256) void ln2_kernel(u16* __restrict__ t, const float* __restrict__ g,
    const float* __restrict__ be){
  __shared__ float red[4];
  int row = blockIdx.x, tid = threadIdx.x;
  const ushort4 xu = *(const ushort4*)&t[(size_t)row*Hn + tid*4];
  float x0 = bf2f(xu.x), x1 = bf2f(xu.y), x2 = bf2f(xu.z), x3 = bf2f(xu.w);
  float s = block_sum256(x0+x1+x2+x3, red);
  float mean = s*(1.0f/Hn);
  float d0=x0-mean, d1=x1-mean, d2=x2-mean, d3=x3-mean;
  float sq = block_sum256(d0*d0+d1*d1+d2*d2+d3*d3, red);
  float rstd = rsqrtf(sq*(1.0f/Hn) + 1e-12f);
  int c = tid*4;
  ushort4 y;
  y.x = f2bf(d0*rstd*g[c+0] + be[c+0]);
  y.y = f2bf(d1*rstd*g[c+1] + be[c+1]);
  y.z = f2bf(d2*rstd*g[c+2] + be[c+2]);
  y.w = f2bf(d3*rstd*g[c+3] + be[c+3]);
  *(ushort4*)&t[(size_t)row*Hn + c] = y;
}

// ---------------- span mean (bf16 input) ----------------
__global__ __launch_bounds__(256) void span_kernel(const u16* __restrict__ y, const int* __restrict__ head,
    const int* __restrict__ tail, float* __restrict__ out){
  int bs = blockIdx.x;
  int b = bs >> 5;
  int hd = head[bs], tl = tail[bs];
  int c = threadIdx.x*4;
  float a0=0.f,a1=0.f,a2=0.f,a3=0.f;
  for (int s=hd; s<tl; ++s){
    const ushort4 v = *(const ushort4*)&y[((size_t)(b*Sn + s))*Hn + c];
    a0+=bf2f(v.x); a1+=bf2f(v.y); a2+=bf2f(v.z); a3+=bf2f(v.w);
  }
  float inv = 1.0f/(float)(tl-hd);
  float4 o; o.x=a0*inv; o.y=a1*inv; o.z=a2*inv; o.w=a3*inv;
  *(float4*)&out[(size_t)bs*Hn + c] = o;
}

extern "C" void kernel_launch(void* const* d_in, const int* in_sizes, int n_in,
                              void* d_out, int out_size, void* d_ws, size_t ws_size,
                              hipStream_t stream) {
  const float* hs    = (const float*)d_in[0];
  const int*   mask  = (const int*)d_in[1];
  const int*   shead = (const int*)d_in[2];
  const int*   stail = (const int*)d_in[3];
  const float* lw    = (const float*)d_in[4];
  const float* ln1g  = (const float*)d_in[5];
  const float* ln1b  = (const float*)d_in[6];
  const float* Wq    = (const float*)d_in[7];
  const float* bq    = (const float*)d_in[8];
  const float* Wk    = (const float*)d_in[9];
  const float* bk    = (const float*)d_in[10];
  const float* Wv    = (const float*)d_in[11];
  const float* bv    = (const float*)d_in[12];
  const float* Wo    = (const float*)d_in[13];
  const float* bo    = (const float*)d_in[14];
  const float* ln2g  = (const float*)d_in[15];
  const float* ln2b  = (const float*)d_in[16];

  char* ws = (char*)d_ws;
  u16* xb  = (u16*)(ws);                 // 32 MiB
  u16* wb  = (u16*)(ws + 33554432);      // 8 MiB (Wq,Wk,Wv,Wo bf16)
  u16* qb  = (u16*)(ws + 41943040);      // 32 MiB
  u16* kb  = (u16*)(ws + 75497472);      // 32 MiB
  u16* vt  = (u16*)(ws + 109051904);     // 32 MiB
  u16* ctx = (u16*)(ws + 142606336);     // 32 MiB ; ends at 176160768
  u16* t   = (u16*)(ws + 41943040);      // 32 MiB bf16, overlays qb (dead after attn)
  float* out = (float*)d_out;

  convw_kernel<<<dim3(1024,4),256,0,stream>>>(Wq,Wk,Wv,Wo,wb);
  mixln_kernel<<<Mn,256,0,stream>>>(hs,lw,ln1g,ln1b,xb);
  gemm256_kernel<0><<<256,512,0,stream>>>(xb, wb,           bq, nullptr, qb, 0.044194173824159223f);
  gemm256_kernel<0><<<256,512,0,stream>>>(xb, wb+1048576,   bk, nullptr, kb, 1.0f);
  gemm256_kernel<1><<<256,512,0,stream>>>(xb, wb+2097152,   bv, nullptr, vt, 1.0f);
  attn_kernel<<<256,512,0,stream>>>(qb,kb,vt,mask,ctx);
  gemm256_kernel<2><<<256,512,0,stream>>>(ctx, wb+3145728,  bo, xb, t, 1.0f);
  ln2_kernel<<<Mn,256,0,stream>>>(t, ln2g, ln2b);
  span_kernel<<<Bn*NSn,256,0,stream>>>(t, shead, stail, out);
}

// Round 15
// 540.904 us; speedup vs baseline: 1.4378x; 1.0686x over previous
//
#include <hip/hip_runtime.h>
#include <stdint.h>

#define Ln 4
#define Bn 8
#define Sn 2048
#define Hn 1024
#define NHn 2
#define DHn 512
#define NSn 32
#define Mn (Bn*Sn)

typedef __attribute__((ext_vector_type(8))) short bf16x8;
typedef __attribute__((ext_vector_type(4))) float f32x4;
typedef unsigned short u16;

__device__ __forceinline__ float bf2f(u16 u){
  union { unsigned int i; float f; } c; c.i = ((unsigned int)u)<<16; return c.f;
}
__device__ __forceinline__ u16 f2bf(float f){
  union { float f; unsigned int i; } c; c.f = f;
  unsigned int r = c.i + 0x7FFFu + ((c.i>>16)&1u);
  return (u16)(r>>16);
}
__device__ __forceinline__ uint32_t packbf(float a, float b){
  return (uint32_t)f2bf(a) | ((uint32_t)f2bf(b)<<16);
}
__device__ __forceinline__ void gl2lds16(const void* g, void* l){
  __builtin_amdgcn_global_load_lds((const __attribute__((address_space(1))) void*)g,
                                   (__attribute__((address_space(3))) void*)l, 16, 0, 0);
}

__device__ __forceinline__ float block_sum256(float v, float* red){
#pragma unroll
  for (int m=32;m>=1;m>>=1) v += __shfl_xor(v, m, 64);
  int tid = threadIdx.x;
  if ((tid&63)==0) red[tid>>6] = v;
  __syncthreads();
  v = red[0]+red[1]+red[2]+red[3];
  __syncthreads();
  return v;
}

// ---------------- weight f32 -> bf16 ----------------
__global__ __launch_bounds__(256) void convw_kernel(const float* __restrict__ Wq, const float* __restrict__ Wk,
    const float* __restrict__ Wv, const float* __restrict__ Wo, u16* __restrict__ wb){
  int m = blockIdx.y;
  const float* src = (m==0)?Wq:(m==1)?Wk:(m==2)?Wv:Wo;
  size_t i = ((size_t)blockIdx.x*256 + threadIdx.x)*4;
  const float4 v = *(const float4*)&src[i];
  ushort4 o;
  o.x=f2bf(v.x); o.y=f2bf(v.y); o.z=f2bf(v.z); o.w=f2bf(v.w);
  *(ushort4*)&wb[(size_t)m*Hn*Hn + i] = o;
}

// ---------------- layer mix + LN1 -> x (bf16) ----------------
__global__ __launch_bounds__(256) void mixln_kernel(const float* __restrict__ hs, const float* __restrict__ lw,
    const float* __restrict__ g, const float* __restrict__ be, u16* __restrict__ xb){
  __shared__ float red[4];
  int row = blockIdx.x;
  int tid = threadIdx.x;
  float l0=lw[0], l1=lw[1], l2=lw[2], l3=lw[3];
  float mx = fmaxf(fmaxf(l0,l1),fmaxf(l2,l3));
  float e0=__expf(l0-mx), e1=__expf(l1-mx), e2=__expf(l2-mx), e3=__expf(l3-mx);
  float inv = 1.0f/(e0+e1+e2+e3);
  e0*=inv; e1*=inv; e2*=inv; e3*=inv;
  size_t base = (size_t)row*Hn + tid*4;
  const float4 h0 = *(const float4*)&hs[base];
  const float4 h1 = *(const float4*)&hs[base + (size_t)Mn*Hn];
  const float4 h2 = *(const float4*)&hs[base + (size_t)2*Mn*Hn];
  const float4 h3 = *(const float4*)&hs[base + (size_t)3*Mn*Hn];
  float x0 = e0*h0.x + e1*h1.x + e2*h2.x + e3*h3.x;
  float x1 = e0*h0.y + e1*h1.y + e2*h2.y + e3*h3.y;
  float x2 = e0*h0.z + e1*h1.z + e2*h2.z + e3*h3.z;
  float x3 = e0*h0.w + e1*h1.w + e2*h2.w + e3*h3.w;
  float s = block_sum256(x0+x1+x2+x3, red);
  float mean = s * (1.0f/Hn);
  float d0=x0-mean, d1=x1-mean, d2=x2-mean, d3=x3-mean;
  float sq = block_sum256(d0*d0+d1*d1+d2*d2+d3*d3, red);
  float rstd = rsqrtf(sq*(1.0f/Hn) + 1e-7f);
  int c = tid*4;
  ushort4 o;
  o.x = f2bf(d0*rstd*g[c+0] + be[c+0]);
  o.y = f2bf(d1*rstd*g[c+1] + be[c+1]);
  o.z = f2bf(d2*rstd*g[c+2] + be[c+2]);
  o.w = f2bf(d3*rstd*g[c+3] + be[c+3]);
  *(ushort4*)&xb[(size_t)row*Hn + c] = o;
}

// ---------------- GEMM 256x256, BK=64x2 per iter, 8-phase counted-vmcnt (validated) ----------------
template<int MODE>
__global__ __launch_bounds__(512,2) void gemm256_kernel(const u16* __restrict__ A, const u16* __restrict__ Bw,
    const float* __restrict__ bias, const u16* __restrict__ resid, void* __restrict__ Cout, float scale){
  __shared__ char ldsb[131072];   // [buf][A/B][half][128x64 bf16 = 16KB]
  int tid = threadIdx.x, lane = tid&63, wid = tid>>6;
  int ln = lane&15, g4 = lane>>4;
  int wm = wid>>2, wn = wid&3;        // wave grid 2M x 4N; per-wave out 128x64
  int swz = (blockIdx.x&7)*32 + (blockIdx.x>>3);
  int i0 = (swz>>2)*256;
  int j0 = (swz&3)*256;

  f32x4 acc[8][4];
#pragma unroll
  for (int a=0;a<8;a++)
#pragma unroll
    for (int b=0;b<4;b++) acc[a][b] = (f32x4){0.f,0.f,0.f,0.f};

  const u16* Asrc = A + (size_t)i0*Hn;
  const u16* Bsrc = Bw + (size_t)j0*Hn;
  const int hA = wm, hB = wn>>1, bB = (wn&1)*64;

#define LDSOFF(B,AB,H) ((((B)*2+(AB))*2+(H))*16384)
#define STG(AB,H,B,T) do { \
    const u16* s_ = (AB) ? Bsrc : Asrc; \
    char* d_ = ldsb + LDSOFF(B,AB,H); \
    _Pragma("unroll") \
    for (int l_=0;l_<2;++l_){ \
      int g_ = l_*512 + tid; int r_ = g_>>3; int cs_ = (g_&7) ^ (r_&7); \
      gl2lds16(s_ + (size_t)((H)*128 + r_)*Hn + (T)*64 + cs_*8, d_ + g_*16); \
    } } while(0)
#define RDH(B,AB,H,RR,KG) (*(const bf16x8*)(ldsb + LDSOFF(B,AB,H) + (RR)*128 + ((((KG)) ^ ((RR)&7))<<4)))
#define LOADA(B,I) { _Pragma("unroll") for (int mt=0;mt<4;++mt) \
    _Pragma("unroll") for (int kk=0;kk<2;++kk) af[mt][kk] = RDH(B,0,hA,(I)*64+mt*16+ln, kk*4+g4); }
#define LOADB(B,ARR,J) { _Pragma("unroll") for (int nt=0;nt<2;++nt) \
    _Pragma("unroll") for (int kk=0;kk<2;++kk) ARR[nt][kk] = RDH(B,1,hB, bB+((J)*2+nt)*16+ln, kk*4+g4); }
#define PH_OPEN __builtin_amdgcn_s_barrier(); \
    asm volatile("s_waitcnt lgkmcnt(0)" ::: "memory"); \
    __builtin_amdgcn_sched_barrier(0);
#define MM(I,J,BF) { __builtin_amdgcn_s_setprio(1); \
    _Pragma("unroll") for (int kk=0;kk<2;++kk) \
    _Pragma("unroll") for (int mt=0;mt<4;++mt) \
    _Pragma("unroll") for (int nt=0;nt<2;++nt) \
      acc[(I)*4+mt][(J)*2+nt] = __builtin_amdgcn_mfma_f32_16x16x32_bf16(af[mt][kk], BF[nt][kk], acc[(I)*4+mt][(J)*2+nt], 0,0,0); \
    __builtin_amdgcn_s_setprio(0); }
#define PH_CLOSE __builtin_amdgcn_s_barrier();

  STG(0,0,0,0); STG(0,1,0,0); STG(1,0,0,0); STG(1,1,0,0);
  STG(0,0,1,1);
  asm volatile("s_waitcnt vmcnt(2)" ::: "memory");
  __builtin_amdgcn_s_barrier();

  bf16x8 af[4][2], bf0[2][2], bf1[2][2];
#pragma unroll 1
  for (int it=0; it<8; ++it){
    const int u = 2*it, v = 2*it+1;
    const bool st = (it < 7);
    LOADA(0,0); LOADB(0,bf0,0);
    STG(0,1,1,v);
    PH_OPEN; MM(0,0,bf0); PH_CLOSE;
    LOADB(0,bf1,1);
    STG(1,0,1,v);
    PH_OPEN; MM(0,1,bf1); PH_CLOSE;
    LOADA(0,1);
    STG(1,1,1,v);
    PH_OPEN; MM(1,0,bf0); PH_CLOSE;
    if (st) STG(0,0,0,u+2);
    PH_OPEN; MM(1,1,bf1);
    if (st) { asm volatile("s_waitcnt vmcnt(2)" ::: "memory"); }
    else    { asm volatile("s_waitcnt vmcnt(0)" ::: "memory"); }
    PH_CLOSE;
    LOADA(1,0); LOADB(1,bf0,0);
    if (st) STG(0,1,0,u+2);
    PH_OPEN; MM(0,0,bf0); PH_CLOSE;
    LOADB(1,bf1,1);
    if (st) STG(1,0,0,u+2);
    PH_OPEN; MM(0,1,bf1); PH_CLOSE;
    LOADA(1,1);
    if (st) STG(1,1,0,u+2);
    PH_OPEN; MM(1,0,bf0); PH_CLOSE;
    if (st) STG(0,0,1,v+2);
    PH_OPEN; MM(1,1,bf1);
    if (st) { asm volatile("s_waitcnt vmcnt(2)" ::: "memory"); }
    else    { asm volatile("s_waitcnt vmcnt(0)" ::: "memory"); }
    PH_CLOSE;
  }
#undef LDSOFF
#undef STG
#undef RDH
#undef LOADA
#undef LOADB
#undef PH_OPEN
#undef MM
#undef PH_CLOSE

#pragma unroll
  for (int mt=0; mt<8; ++mt){
#pragma unroll
    for (int nt=0; nt<4; ++nt){
#pragma unroll
      for (int r=0; r<4; ++r){
        int i = i0 + wm*128 + mt*16 + g4*4 + r;
        int j = j0 + wn*64 + nt*16 + ln;
        float v = acc[mt][nt][r] + bias[j];
        if (MODE==0){
          int b = i>>11, s = i&2047, nh = j>>9, dh = j&511;
          ((u16*)Cout)[(((size_t)(b*NHn+nh)*Sn + s)<<9) + dh] = f2bf(v*scale);
        } else if (MODE==1){
          int b = i>>11, s = i&2047, nh = j>>9, dh = j&511;
          ((u16*)Cout)[((size_t)((b*NHn+nh)*(Sn/32) + (s>>5))<<14) + (dh<<5) + (s&31)] = f2bf(v);
        } else {
          float res = bf2f(resid[(size_t)i*Hn + j]);
          ((u16*)Cout)[(size_t)i*Hn + j] = f2bf(v + res);
        }
      }
    }
  }
}

// ---------------- flash attention (R10 structure — best measured: ~227us) ----------------
__global__ __launch_bounds__(512,2) void attn_kernel(const u16* __restrict__ qb, const u16* __restrict__ kb,
    const u16* __restrict__ vt, const int* __restrict__ mask, u16* __restrict__ ctx){
  __shared__ u16 Ks[2][32*512];  // 2x32KB, row-swizzled
  __shared__ u16 Vs[2][512*32];  // 2x32KB, tiled V^T (d, k%32), granule-swizzled
  __shared__ u16 Ps[8*16*32];    // block-shared P[128q][32k], wave-region + granule-swizzled
  __shared__ float Lcorr[128];   // per-q rescale factor (1.0 if none)
  __shared__ float Lflag[8];     // per-wave rescale flag
  __shared__ float Linv[128];    // per-q 1/l (epilogue)
  int tid = threadIdx.x, lane = tid&63, wid = tid>>6;
  int ln = lane&15, g4 = lane>>4;
  int gid = blockIdx.x;
  int xcd = gid&7, ord = gid>>3;
  int bh = xcd*2 + (ord>>4), qt = ord&15;   // 16 qt-blocks of one bh share an XCD
  int b = bh >> 1, nh = bh & 1;
  u16* pw = Ps + wid*512;
  uint32_t* pw32 = (uint32_t*)pw;
  const int swz = (ln&7)<<4;
  const int rsw = (ln>>1)&3;     // P/V swizzle key

  bf16x8 aq[16];
  size_t qoff = ((size_t)bh*Sn + qt*128 + wid*16 + ln)*DHn + g4*8;
#pragma unroll
  for (int ch=0; ch<16; ++ch) aq[ch] = *(const bf16x8*)&qb[qoff + ch*32];

  // o2[qf][df]: q = qf*16 + g4*4 + r ; d = wid*64 + df*16 + ln
  f32x4 o2[8][4];
#pragma unroll
  for (int qf=0; qf<8; ++qf)
#pragma unroll
    for (int df=0; df<4; ++df) o2[qf][df] = (f32x4){0.f,0.f,0.f,0.f};
  float mrun = -1e30f, lrun = 0.f;

  const size_t kbase = (size_t)bh*Sn*DHn;
  const u16* vtile = vt + (size_t)bh*Sn*DHn;   // tiled V^T: [kt][512 d][32 k]

#define STAGE_KV(KT,BUF) do { \
  _Pragma("unroll") \
  for (int t_=0; t_<4; ++t_){ \
    int krow_ = t_*8 + wid; \
    int koff_ = (lane*16) ^ ((krow_&7)<<4); \
    gl2lds16(&kb[kbase + ((size_t)((KT)*32 + krow_))*DHn + (koff_>>1)], \
             (char*)Ks[BUF] + krow_*1024 + lane*16); \
  } \
  _Pragma("unroll") \
  for (int t_=0; t_<4; ++t_){ \
    int p_ = t_*512 + tid; \
    int cgd_ = ((p_&3) ^ ((p_>>3)&3)); \
    gl2lds16(&vtile[(size_t)(KT)*16384 + (p_&~3)*8 + cgd_*8], \
             (char*)Vs[BUF] + p_*16); \
  } } while(0)

  STAGE_KV(0,0);
  __syncthreads();   // tile 0 resident
#pragma unroll 1
  for (int kt=0; kt<Sn/32; ++kt){
    int cur = kt&1;
    if (kt < Sn/32 - 1) STAGE_KV(kt+1, cur^1);   // DMA spans the raw barrier; drained at end sync
    const char* KsB = (const char*)Ks[cur];
    f32x4 s0 = (f32x4){0.f,0.f,0.f,0.f};
    f32x4 s1 = (f32x4){0.f,0.f,0.f,0.f};
#pragma unroll
    for (int ch=0; ch<16; ++ch){
      bf16x8 k0 = *(const bf16x8*)(KsB + ln*1024      + ((ch*64 + g4*16) ^ swz));
      bf16x8 k1 = *(const bf16x8*)(KsB + (16+ln)*1024 + ((ch*64 + g4*16) ^ swz));
      s0 = __builtin_amdgcn_mfma_f32_16x16x32_bf16(k0, aq[ch], s0, 0,0,0);
      s1 = __builtin_amdgcn_mfma_f32_16x16x32_bf16(k1, aq[ch], s1, 0,0,0);
    }
    int4 mk0 = *(const int4*)&mask[b*Sn + kt*32 + g4*4];
    int4 mk1 = *(const int4*)&mask[b*Sn + kt*32 + 16 + g4*4];
    s0[0] += (float)(1-mk0.x)*-10000.0f; s0[1] += (float)(1-mk0.y)*-10000.0f;
    s0[2] += (float)(1-mk0.z)*-10000.0f; s0[3] += (float)(1-mk0.w)*-10000.0f;
    s1[0] += (float)(1-mk1.x)*-10000.0f; s1[1] += (float)(1-mk1.y)*-10000.0f;
    s1[2] += (float)(1-mk1.z)*-10000.0f; s1[3] += (float)(1-mk1.w)*-10000.0f;
    float tmax = fmaxf(fmaxf(fmaxf(s0[0],s0[1]),fmaxf(s0[2],s0[3])),
                       fmaxf(fmaxf(s1[0],s1[1]),fmaxf(s1[2],s1[3])));
    tmax = fmaxf(tmax, __shfl_xor(tmax, 16));
    tmax = fmaxf(tmax, __shfl_xor(tmax, 32));
    float corr = 1.0f, wflag = 0.0f;
    if (__any(tmax > mrun + 8.0f)){     // defer-max: rare rescale
      float nm = fmaxf(mrun, tmax);
      corr = __expf(mrun - nm);
      mrun = nm; lrun *= corr;
      wflag = 1.0f;
    }
    float p0=__expf(s0[0]-mrun), p1=__expf(s0[1]-mrun), p2=__expf(s0[2]-mrun), p3=__expf(s0[3]-mrun);
    float p4=__expf(s1[0]-mrun), p5=__expf(s1[1]-mrun), p6=__expf(s1[2]-mrun), p7=__expf(s1[3]-mrun);
    float sum = ((p0+p1)+(p2+p3)) + ((p4+p5)+(p6+p7));
    sum += __shfl_xor(sum, 16);
    sum += __shfl_xor(sum, 32);
    lrun += sum;
    // P write: swizzled granules — granule (q,gr) at u16 q*32 + (gr^((q>>1)&3))*8.
    {
      int base = ln*16 + ((g4&1)<<1);
      pw32[base + (((g4>>1)    ^rsw)<<2)    ] = packbf(p0,p1);
      pw32[base + (((g4>>1)    ^rsw)<<2) + 1] = packbf(p2,p3);
      pw32[base + ((((g4>>1)+2)^rsw)<<2)    ] = packbf(p4,p5);
      pw32[base + ((((g4>>1)+2)^rsw)<<2) + 1] = packbf(p6,p7);
    }
    if (lane < 16) Lcorr[wid*16 + ln] = corr;
    if (lane == 0) Lflag[wid] = wflag;
    // ---- mid-iter barrier: DS visibility only; staging DMA stays in flight
    __builtin_amdgcn_sched_barrier(0);
    asm volatile("s_waitcnt lgkmcnt(0)" ::: "memory");
    __builtin_amdgcn_s_barrier();
    __builtin_amdgcn_sched_barrier(0);
    // ---- cross-wave rescale (rare)
    {
      f32x4 fl0 = *(const f32x4*)&Lflag[0];
      f32x4 fl1 = *(const f32x4*)&Lflag[4];
      float fs = (fl0[0]+fl0[1]+fl0[2]+fl0[3]) + (fl1[0]+fl1[1]+fl1[2]+fl1[3]);
      if (fs > 0.5f){
#pragma unroll
        for (int qf=0; qf<8; ++qf){
          f32x4 c4 = *(const f32x4*)&Lcorr[qf*16 + g4*4];
#pragma unroll
          for (int df=0; df<4; ++df){
            o2[qf][df][0]*=c4[0]; o2[qf][df][1]*=c4[1];
            o2[qf][df][2]*=c4[2]; o2[qf][df][3]*=c4[3];
          }
        }
      }
    }
    // ---- PV: wave computes all 128 q for its 64-wide d-slice
    const char* VsB = (const char*)Vs[cur];
    bf16x8 bv[4];
#pragma unroll
    for (int df=0; df<4; ++df)
      bv[df] = *(const bf16x8*)(VsB + ((wid*4+df)*16+ln)*64 + ((g4 ^ rsw)<<4));
#pragma unroll
    for (int qf=0; qf<8; ++qf){
      bf16x8 aP = *(const bf16x8*)&Ps[qf*512 + ln*32 + ((g4 ^ rsw)<<3)];
#pragma unroll
      for (int df=0; df<4; ++df)
        o2[qf][df] = __builtin_amdgcn_mfma_f32_16x16x32_bf16(aP, bv[df], o2[qf][df], 0,0,0);
    }
    __syncthreads();   // drains vmcnt(0): tile kt+1 landed; all reads of cur done
  }
#undef STAGE_KV
  if (lane < 16) Linv[wid*16 + ln] = 1.0f/lrun;
  __syncthreads();
  int qr0 = qt*128;
#pragma unroll
  for (int qf=0; qf<8; ++qf){
    f32x4 il4 = *(const f32x4*)&Linv[qf*16 + g4*4];
#pragma unroll
    for (int df=0; df<4; ++df){
#pragma unroll
      for (int r=0; r<4; ++r){
        int q = qr0 + qf*16 + g4*4 + r;
        int d = nh*DHn + wid*64 + df*16 + ln;
        ctx[((size_t)(b*Sn + q))*Hn + d] = f2bf(o2[qf][df][r]*il4[r]);
      }
    }
  }
}

// ---------------- LN2 in-place on bf16, wave-per-row (no barriers/LDS) ----------------
__global__ __launch_bounds__(256) void ln2_kernel(u16* __restrict__ t, const float* __restrict__ g,
    const float* __restrict__ be){
  int lane = threadIdx.x&63, wid = threadIdx.x>>6;
  int row = blockIdx.x*4 + wid;
  u16* rp = t + (size_t)row*Hn;
  float x[16];
#pragma unroll
  for (int c=0;c<4;++c){
    const ushort4 xu = *(const ushort4*)&rp[lane*4 + c*256];
    x[c*4+0]=bf2f(xu.x); x[c*4+1]=bf2f(xu.y); x[c*4+2]=bf2f(xu.z); x[c*4+3]=bf2f(xu.w);
  }
  float s = 0.f;
#pragma unroll
  for (int e=0;e<16;++e) s += x[e];
#pragma unroll
  for (int m=32;m>=1;m>>=1) s += __shfl_xor(s, m, 64);
  float mean = s*(1.0f/Hn);
  float sq = 0.f;
#pragma unroll
  for (int e=0;e<16;++e){ float d = x[e]-mean; sq += d*d; }
#pragma unroll
  for (int m=32;m>=1;m>>=1) sq += __shfl_xor(sq, m, 64);
  float rstd = rsqrtf(sq*(1.0f/Hn) + 1e-12f);
#pragma unroll
  for (int c=0;c<4;++c){
    int col = lane*4 + c*256;
    ushort4 y;
    y.x = f2bf((x[c*4+0]-mean)*rstd*g[col+0] + be[col+0]);
    y.y = f2bf((x[c*4+1]-mean)*rstd*g[col+1] + be[col+1]);
    y.z = f2bf((x[c*4+2]-mean)*rstd*g[col+2] + be[col+2]);
    y.w = f2bf((x[c*4+3]-mean)*rstd*g[col+3] + be[col+3]);
    *(ushort4*)&rp[col] = y;
  }
}

// ---------------- span mean (bf16 input) ----------------
__global__ __launch_bounds__(256) void span_kernel(const u16* __restrict__ y, const int* __restrict__ head,
    const int* __restrict__ tail, float* __restrict__ out){
  int bs = blockIdx.x;
  int b = bs >> 5;
  int hd = head[bs], tl = tail[bs];
  int c = threadIdx.x*4;
  float a0=0.f,a1=0.f,a2=0.f,a3=0.f;
  for (int s=hd; s<tl; ++s){
    const ushort4 v = *(const ushort4*)&y[((size_t)(b*Sn + s))*Hn + c];
    a0+=bf2f(v.x); a1+=bf2f(v.y); a2+=bf2f(v.z); a3+=bf2f(v.w);
  }
  float inv = 1.0f/(float)(tl-hd);
  float4 o; o.x=a0*inv; o.y=a1*inv; o.z=a2*inv; o.w=a3*inv;
  *(float4*)&out[(size_t)bs*Hn + c] = o;
}

extern "C" void kernel_launch(void* const* d_in, const int* in_sizes, int n_in,
                              void* d_out, int out_size, void* d_ws, size_t ws_size,
                              hipStream_t stream) {
  const float* hs    = (const float*)d_in[0];
  const int*   mask  = (const int*)d_in[1];
  const int*   shead = (const int*)d_in[2];
  const int*   stail = (const int*)d_in[3];
  const float* lw    = (const float*)d_in[4];
  const float* ln1g  = (const float*)d_in[5];
  const float* ln1b  = (const float*)d_in[6];
  const float* Wq    = (const float*)d_in[7];
  const float* bq    = (const float*)d_in[8];
  const float* Wk    = (const float*)d_in[9];
  const float* bk    = (const float*)d_in[10];
  const float* Wv    = (const float*)d_in[11];
  const float* bv    = (const float*)d_in[12];
  const float* Wo    = (const float*)d_in[13];
  const float* bo    = (const float*)d_in[14];
  const float* ln2g  = (const float*)d_in[15];
  const float* ln2b  = (const float*)d_in[16];

  char* ws = (char*)d_ws;
  u16* xb  = (u16*)(ws);                 // 32 MiB
  u16* wb  = (u16*)(ws + 33554432);      // 8 MiB (Wq,Wk,Wv,Wo bf16)
  u16* qb  = (u16*)(ws + 41943040);      // 32 MiB
  u16* kb  = (u16*)(ws + 75497472);      // 32 MiB
  u16* vt  = (u16*)(ws + 109051904);     // 32 MiB
  u16* ctx = (u16*)(ws + 142606336);     // 32 MiB ; ends at 176160768
  u16* t   = (u16*)(ws + 41943040);      // 32 MiB bf16, overlays qb (dead after attn)
  float* out = (float*)d_out;

  convw_kernel<<<dim3(1024,4),256,0,stream>>>(Wq,Wk,Wv,Wo,wb);
  mixln_kernel<<<Mn,256,0,stream>>>(hs,lw,ln1g,ln1b,xb);
  gemm256_kernel<0><<<256,512,0,stream>>>(xb, wb,           bq, nullptr, qb, 0.044194173824159223f);
  gemm256_kernel<0><<<256,512,0,stream>>>(xb, wb+1048576,   bk, nullptr, kb, 1.0f);
  gemm256_kernel<1><<<256,512,0,stream>>>(xb, wb+2097152,   bv, nullptr, vt, 1.0f);
  attn_kernel<<<256,512,0,stream>>>(qb,kb,vt,mask,ctx);
  gemm256_kernel<2><<<256,512,0,stream>>>(ctx, wb+3145728,  bo, xb, t, 1.0f);
  ln2_kernel<<<Mn/4,256,0,stream>>>(t, ln2g, ln2b);
  span_kernel<<<Bn*NSn,256,0,stream>>>(t, shead, stail, out);
}

// Round 16
// 464.807 us; speedup vs baseline: 1.6731x; 1.1637x over previous
//
#include <hip/hip_runtime.h>
#include <stdint.h>

#define Ln 4
#define Bn 8
#define Sn 2048
#define Hn 1024
#define NHn 2
#define DHn 512
#define NSn 32
#define Mn (Bn*Sn)

typedef __attribute__((ext_vector_type(8))) short bf16x8;
typedef __attribute__((ext_vector_type(4))) float f32x4;
typedef unsigned short u16;

__device__ __forceinline__ float bf2f(u16 u){
  union { unsigned int i; float f; } c; c.i = ((unsigned int)u)<<16; return c.f;
}
__device__ __forceinline__ u16 f2bf(float f){
  union { float f; unsigned int i; } c; c.f = f;
  unsigned int r = c.i + 0x7FFFu + ((c.i>>16)&1u);
  return (u16)(r>>16);
}
__device__ __forceinline__ uint32_t packbf(float a, float b){
  return (uint32_t)f2bf(a) | ((uint32_t)f2bf(b)<<16);
}
__device__ __forceinline__ void gl2lds16(const void* g, void* l){
  __builtin_amdgcn_global_load_lds((const __attribute__((address_space(1))) void*)g,
                                   (__attribute__((address_space(3))) void*)l, 16, 0, 0);
}

__device__ __forceinline__ float block_sum256(float v, float* red){
#pragma unroll
  for (int m=32;m>=1;m>>=1) v += __shfl_xor(v, m, 64);
  int tid = threadIdx.x;
  if ((tid&63)==0) red[tid>>6] = v;
  __syncthreads();
  v = red[0]+red[1]+red[2]+red[3];
  __syncthreads();
  return v;
}

// ---------------- weight f32 -> bf16 ----------------
__global__ __launch_bounds__(256) void convw_kernel(const float* __restrict__ Wq, const float* __restrict__ Wk,
    const float* __restrict__ Wv, const float* __restrict__ Wo, u16* __restrict__ wb){
  int m = blockIdx.y;
  const float* src = (m==0)?Wq:(m==1)?Wk:(m==2)?Wv:Wo;
  size_t i = ((size_t)blockIdx.x*256 + threadIdx.x)*4;
  const float4 v = *(const float4*)&src[i];
  ushort4 o;
  o.x=f2bf(v.x); o.y=f2bf(v.y); o.z=f2bf(v.z); o.w=f2bf(v.w);
  *(ushort4*)&wb[(size_t)m*Hn*Hn + i] = o;
}

// ---------------- layer mix + LN1 -> x (bf16) ----------------
__global__ __launch_bounds__(256) void mixln_kernel(const float* __restrict__ hs, const float* __restrict__ lw,
    const float* __restrict__ g, const float* __restrict__ be, u16* __restrict__ xb){
  __shared__ float red[4];
  int row = blockIdx.x;
  int tid = threadIdx.x;
  float l0=lw[0], l1=lw[1], l2=lw[2], l3=lw[3];
  float mx = fmaxf(fmaxf(l0,l1),fmaxf(l2,l3));
  float e0=__expf(l0-mx), e1=__expf(l1-mx), e2=__expf(l2-mx), e3=__expf(l3-mx);
  float inv = 1.0f/(e0+e1+e2+e3);
  e0*=inv; e1*=inv; e2*=inv; e3*=inv;
  size_t base = (size_t)row*Hn + tid*4;
  const float4 h0 = *(const float4*)&hs[base];
  const float4 h1 = *(const float4*)&hs[base + (size_t)Mn*Hn];
  const float4 h2 = *(const float4*)&hs[base + (size_t)2*Mn*Hn];
  const float4 h3 = *(const float4*)&hs[base + (size_t)3*Mn*Hn];
  float x0 = e0*h0.x + e1*h1.x + e2*h2.x + e3*h3.x;
  float x1 = e0*h0.y + e1*h1.y + e2*h2.y + e3*h3.y;
  float x2 = e0*h0.z + e1*h1.z + e2*h2.z + e3*h3.z;
  float x3 = e0*h0.w + e1*h1.w + e2*h2.w + e3*h3.w;
  float s = block_sum256(x0+x1+x2+x3, red);
  float mean = s * (1.0f/Hn);
  float d0=x0-mean, d1=x1-mean, d2=x2-mean, d3=x3-mean;
  float sq = block_sum256(d0*d0+d1*d1+d2*d2+d3*d3, red);
  float rstd = rsqrtf(sq*(1.0f/Hn) + 1e-7f);
  int c = tid*4;
  ushort4 o;
  o.x = f2bf(d0*rstd*g[c+0] + be[c+0]);
  o.y = f2bf(d1*rstd*g[c+1] + be[c+1]);
  o.z = f2bf(d2*rstd*g[c+2] + be[c+2]);
  o.w = f2bf(d3*rstd*g[c+3] + be[c+3]);
  *(ushort4*)&xb[(size_t)row*Hn + c] = o;
}

// ---------------- GEMM 256x256, BK=64x2 per iter, 8-phase counted-vmcnt (validated) ----------------
template<int MODE>
__global__ __launch_bounds__(512,2) void gemm256_kernel(const u16* __restrict__ A, const u16* __restrict__ Bw,
    const float* __restrict__ bias, const u16* __restrict__ resid, void* __restrict__ Cout, float scale){
  __shared__ char ldsb[131072];   // [buf][A/B][half][128x64 bf16 = 16KB]
  int tid = threadIdx.x, lane = tid&63, wid = tid>>6;
  int ln = lane&15, g4 = lane>>4;
  int wm = wid>>2, wn = wid&3;        // wave grid 2M x 4N; per-wave out 128x64
  int swz = (blockIdx.x&7)*32 + (blockIdx.x>>3);
  int i0 = (swz>>2)*256;
  int j0 = (swz&3)*256;

  f32x4 acc[8][4];
#pragma unroll
  for (int a=0;a<8;a++)
#pragma unroll
    for (int b=0;b<4;b++) acc[a][b] = (f32x4){0.f,0.f,0.f,0.f};

  const u16* Asrc = A + (size_t)i0*Hn;
  const u16* Bsrc = Bw + (size_t)j0*Hn;
  const int hA = wm, hB = wn>>1, bB = (wn&1)*64;

#define LDSOFF(B,AB,H) ((((B)*2+(AB))*2+(H))*16384)
#define STG(AB,H,B,T) do { \
    const u16* s_ = (AB) ? Bsrc : Asrc; \
    char* d_ = ldsb + LDSOFF(B,AB,H); \
    _Pragma("unroll") \
    for (int l_=0;l_<2;++l_){ \
      int g_ = l_*512 + tid; int r_ = g_>>3; int cs_ = (g_&7) ^ (r_&7); \
      gl2lds16(s_ + (size_t)((H)*128 + r_)*Hn + (T)*64 + cs_*8, d_ + g_*16); \
    } } while(0)
#define RDH(B,AB,H,RR,KG) (*(const bf16x8*)(ldsb + LDSOFF(B,AB,H) + (RR)*128 + ((((KG)) ^ ((RR)&7))<<4)))
#define LOADA(B,I) { _Pragma("unroll") for (int mt=0;mt<4;++mt) \
    _Pragma("unroll") for (int kk=0;kk<2;++kk) af[mt][kk] = RDH(B,0,hA,(I)*64+mt*16+ln, kk*4+g4); }
#define LOADB(B,ARR,J) { _Pragma("unroll") for (int nt=0;nt<2;++nt) \
    _Pragma("unroll") for (int kk=0;kk<2;++kk) ARR[nt][kk] = RDH(B,1,hB, bB+((J)*2+nt)*16+ln, kk*4+g4); }
#define PH_OPEN __builtin_amdgcn_s_barrier(); \
    asm volatile("s_waitcnt lgkmcnt(0)" ::: "memory"); \
    __builtin_amdgcn_sched_barrier(0);
#define MM(I,J,BF) { __builtin_amdgcn_s_setprio(1); \
    _Pragma("unroll") for (int kk=0;kk<2;++kk) \
    _Pragma("unroll") for (int mt=0;mt<4;++mt) \
    _Pragma("unroll") for (int nt=0;nt<2;++nt) \
      acc[(I)*4+mt][(J)*2+nt] = __builtin_amdgcn_mfma_f32_16x16x32_bf16(af[mt][kk], BF[nt][kk], acc[(I)*4+mt][(J)*2+nt], 0,0,0); \
    __builtin_amdgcn_s_setprio(0); }
#define PH_CLOSE __builtin_amdgcn_s_barrier();

  STG(0,0,0,0); STG(0,1,0,0); STG(1,0,0,0); STG(1,1,0,0);
  STG(0,0,1,1);
  asm volatile("s_waitcnt vmcnt(2)" ::: "memory");
  __builtin_amdgcn_s_barrier();

  bf16x8 af[4][2], bf0[2][2], bf1[2][2];
#pragma unroll 1
  for (int it=0; it<8; ++it){
    const int u = 2*it, v = 2*it+1;
    const bool st = (it < 7);
    LOADA(0,0); LOADB(0,bf0,0);
    STG(0,1,1,v);
    PH_OPEN; MM(0,0,bf0); PH_CLOSE;
    LOADB(0,bf1,1);
    STG(1,0,1,v);
    PH_OPEN; MM(0,1,bf1); PH_CLOSE;
    LOADA(0,1);
    STG(1,1,1,v);
    PH_OPEN; MM(1,0,bf0); PH_CLOSE;
    if (st) STG(0,0,0,u+2);
    PH_OPEN; MM(1,1,bf1);
    if (st) { asm volatile("s_waitcnt vmcnt(2)" ::: "memory"); }
    else    { asm volatile("s_waitcnt vmcnt(0)" ::: "memory"); }
    PH_CLOSE;
    LOADA(1,0); LOADB(1,bf0,0);
    if (st) STG(0,1,0,u+2);
    PH_OPEN; MM(0,0,bf0); PH_CLOSE;
    LOADB(1,bf1,1);
    if (st) STG(1,0,0,u+2);
    PH_OPEN; MM(0,1,bf1); PH_CLOSE;
    LOADA(1,1);
    if (st) STG(1,1,0,u+2);
    PH_OPEN; MM(1,0,bf0); PH_CLOSE;
    if (st) STG(0,0,1,v+2);
    PH_OPEN; MM(1,1,bf1);
    if (st) { asm volatile("s_waitcnt vmcnt(2)" ::: "memory"); }
    else    { asm volatile("s_waitcnt vmcnt(0)" ::: "memory"); }
    PH_CLOSE;
  }
#undef LDSOFF
#undef STG
#undef RDH
#undef LOADA
#undef LOADB
#undef PH_OPEN
#undef MM
#undef PH_CLOSE

#pragma unroll
  for (int mt=0; mt<8; ++mt){
#pragma unroll
    for (int nt=0; nt<4; ++nt){
#pragma unroll
      for (int r=0; r<4; ++r){
        int i = i0 + wm*128 + mt*16 + g4*4 + r;
        int j = j0 + wn*64 + nt*16 + ln;
        float v = acc[mt][nt][r] + bias[j];
        if (MODE==0){
          int b = i>>11, s = i&2047, nh = j>>9, dh = j&511;
          ((u16*)Cout)[(((size_t)(b*NHn+nh)*Sn + s)<<9) + dh] = f2bf(v*scale);
        } else if (MODE==1){
          int b = i>>11, s = i&2047, nh = j>>9, dh = j&511;
          ((u16*)Cout)[((size_t)((b*NHn+nh)*(Sn/32) + (s>>5))<<14) + (dh<<5) + (s&31)] = f2bf(v);
        } else {
          float res = bf2f(resid[(size_t)i*Hn + j]);
          ((u16*)Cout)[(size_t)i*Hn + j] = f2bf(v + res);
        }
      }
    }
  }
}

// ---------------- flash attention (R10 structure — best measured: ~227us) ----------------
__global__ __launch_bounds__(512,2) void attn_kernel(const u16* __restrict__ qb, const u16* __restrict__ kb,
    const u16* __restrict__ vt, const int* __restrict__ mask, u16* __restrict__ ctx){
  __shared__ u16 Ks[2][32*512];  // 2x32KB, row-swizzled
  __shared__ u16 Vs[2][512*32];  // 2x32KB, tiled V^T (d, k%32), granule-swizzled
  __shared__ u16 Ps[8*16*32];    // block-shared P[128q][32k], wave-region + granule-swizzled
  __shared__ float Lcorr[128];   // per-q rescale factor (1.0 if none)
  __shared__ float Lflag[8];     // per-wave rescale flag
  __shared__ float Linv[128];    // per-q 1/l (epilogue)
  int tid = threadIdx.x, lane = tid&63, wid = tid>>6;
  int ln = lane&15, g4 = lane>>4;
  int gid = blockIdx.x;
  int xcd = gid&7, ord = gid>>3;
  int bh = xcd*2 + (ord>>4), qt = ord&15;   // 16 qt-blocks of one bh share an XCD
  int b = bh >> 1, nh = bh & 1;
  u16* pw = Ps + wid*512;
  uint32_t* pw32 = (uint32_t*)pw;
  const int swz = (ln&7)<<4;
  const int rsw = (ln>>1)&3;     // P/V swizzle key

  bf16x8 aq[16];
  size_t qoff = ((size_t)bh*Sn + qt*128 + wid*16 + ln)*DHn + g4*8;
#pragma unroll
  for (int ch=0; ch<16; ++ch) aq[ch] = *(const bf16x8*)&qb[qoff + ch*32];

  // o2[qf][df]: q = qf*16 + g4*4 + r ; d = wid*64 + df*16 + ln
  f32x4 o2[8][4];
#pragma unroll
  for (int qf=0; qf<8; ++qf)
#pragma unroll
    for (int df=0; df<4; ++df) o2[qf][df] = (f32x4){0.f,0.f,0.f,0.f};
  float mrun = -1e30f, lrun = 0.f;

  const size_t kbase = (size_t)bh*Sn*DHn;
  const u16* vtile = vt + (size_t)bh*Sn*DHn;   // tiled V^T: [kt][512 d][32 k]

#define STAGE_KV(KT,BUF) do { \
  _Pragma("unroll") \
  for (int t_=0; t_<4; ++t_){ \
    int krow_ = t_*8 + wid; \
    int koff_ = (lane*16) ^ ((krow_&7)<<4); \
    gl2lds16(&kb[kbase + ((size_t)((KT)*32 + krow_))*DHn + (koff_>>1)], \
             (char*)Ks[BUF] + krow_*1024 + lane*16); \
  } \
  _Pragma("unroll") \
  for (int t_=0; t_<4; ++t_){ \
    int p_ = t_*512 + tid; \
    int cgd_ = ((p_&3) ^ ((p_>>3)&3)); \
    gl2lds16(&vtile[(size_t)(KT)*16384 + (p_&~3)*8 + cgd_*8], \
             (char*)Vs[BUF] + p_*16); \
  } } while(0)

  STAGE_KV(0,0);
  __syncthreads();   // tile 0 resident
#pragma unroll 1
  for (int kt=0; kt<Sn/32; ++kt){
    int cur = kt&1;
    if (kt < Sn/32 - 1) STAGE_KV(kt+1, cur^1);   // DMA spans the raw barrier; drained at end sync
    const char* KsB = (const char*)Ks[cur];
    f32x4 s0 = (f32x4){0.f,0.f,0.f,0.f};
    f32x4 s1 = (f32x4){0.f,0.f,0.f,0.f};
#pragma unroll
    for (int ch=0; ch<16; ++ch){
      bf16x8 k0 = *(const bf16x8*)(KsB + ln*1024      + ((ch*64 + g4*16) ^ swz));
      bf16x8 k1 = *(const bf16x8*)(KsB + (16+ln)*1024 + ((ch*64 + g4*16) ^ swz));
      s0 = __builtin_amdgcn_mfma_f32_16x16x32_bf16(k0, aq[ch], s0, 0,0,0);
      s1 = __builtin_amdgcn_mfma_f32_16x16x32_bf16(k1, aq[ch], s1, 0,0,0);
    }
    int4 mk0 = *(const int4*)&mask[b*Sn + kt*32 + g4*4];
    int4 mk1 = *(const int4*)&mask[b*Sn + kt*32 + 16 + g4*4];
    s0[0] += (float)(1-mk0.x)*-10000.0f; s0[1] += (float)(1-mk0.y)*-10000.0f;
    s0[2] += (float)(1-mk0.z)*-10000.0f; s0[3] += (float)(1-mk0.w)*-10000.0f;
    s1[0] += (float)(1-mk1.x)*-10000.0f; s1[1] += (float)(1-mk1.y)*-10000.0f;
    s1[2] += (float)(1-mk1.z)*-10000.0f; s1[3] += (float)(1-mk1.w)*-10000.0f;
    float tmax = fmaxf(fmaxf(fmaxf(s0[0],s0[1]),fmaxf(s0[2],s0[3])),
                       fmaxf(fmaxf(s1[0],s1[1]),fmaxf(s1[2],s1[3])));
    tmax = fmaxf(tmax, __shfl_xor(tmax, 16));
    tmax = fmaxf(tmax, __shfl_xor(tmax, 32));
    float corr = 1.0f, wflag = 0.0f;
    if (__any(tmax > mrun + 8.0f)){     // defer-max: rare rescale
      float nm = fmaxf(mrun, tmax);
      corr = __expf(mrun - nm);
      mrun = nm; lrun *= corr;
      wflag = 1.0f;
    }
    float p0=__expf(s0[0]-mrun), p1=__expf(s0[1]-mrun), p2=__expf(s0[2]-mrun), p3=__expf(s0[3]-mrun);
    float p4=__expf(s1[0]-mrun), p5=__expf(s1[1]-mrun), p6=__expf(s1[2]-mrun), p7=__expf(s1[3]-mrun);
    float sum = ((p0+p1)+(p2+p3)) + ((p4+p5)+(p6+p7));
    sum += __shfl_xor(sum, 16);
    sum += __shfl_xor(sum, 32);
    lrun += sum;
    // P write: swizzled granules — granule (q,gr) at u16 q*32 + (gr^((q>>1)&3))*8.
    {
      int base = ln*16 + ((g4&1)<<1);
      pw32[base + (((g4>>1)    ^rsw)<<2)    ] = packbf(p0,p1);
      pw32[base + (((g4>>1)    ^rsw)<<2) + 1] = packbf(p2,p3);
      pw32[base + ((((g4>>1)+2)^rsw)<<2)    ] = packbf(p4,p5);
      pw32[base + ((((g4>>1)+2)^rsw)<<2) + 1] = packbf(p6,p7);
    }
    if (lane < 16) Lcorr[wid*16 + ln] = corr;
    if (lane == 0) Lflag[wid] = wflag;
    // ---- mid-iter barrier: DS visibility only; staging DMA stays in flight
    __builtin_amdgcn_sched_barrier(0);
    asm volatile("s_waitcnt lgkmcnt(0)" ::: "memory");
    __builtin_amdgcn_s_barrier();
    __builtin_amdgcn_sched_barrier(0);
    // ---- cross-wave rescale (rare)
    {
      f32x4 fl0 = *(const f32x4*)&Lflag[0];
      f32x4 fl1 = *(const f32x4*)&Lflag[4];
      float fs = (fl0[0]+fl0[1]+fl0[2]+fl0[3]) + (fl1[0]+fl1[1]+fl1[2]+fl1[3]);
      if (fs > 0.5f){
#pragma unroll
        for (int qf=0; qf<8; ++qf){
          f32x4 c4 = *(const f32x4*)&Lcorr[qf*16 + g4*4];
#pragma unroll
          for (int df=0; df<4; ++df){
            o2[qf][df][0]*=c4[0]; o2[qf][df][1]*=c4[1];
            o2[qf][df][2]*=c4[2]; o2[qf][df][3]*=c4[3];
          }
        }
      }
    }
    // ---- PV: wave computes all 128 q for its 64-wide d-slice
    const char* VsB = (const char*)Vs[cur];
    bf16x8 bv[4];
#pragma unroll
    for (int df=0; df<4; ++df)
      bv[df] = *(const bf16x8*)(VsB + ((wid*4+df)*16+ln)*64 + ((g4 ^ rsw)<<4));
#pragma unroll
    for (int qf=0; qf<8; ++qf){
      bf16x8 aP = *(const bf16x8*)&Ps[qf*512 + ln*32 + ((g4 ^ rsw)<<3)];
#pragma unroll
      for (int df=0; df<4; ++df)
        o2[qf][df] = __builtin_amdgcn_mfma_f32_16x16x32_bf16(aP, bv[df], o2[qf][df], 0,0,0);
    }
    __syncthreads();   // drains vmcnt(0): tile kt+1 landed; all reads of cur done
  }
#undef STAGE_KV
  if (lane < 16) Linv[wid*16 + ln] = 1.0f/lrun;
  __syncthreads();
  int qr0 = qt*128;
#pragma unroll
  for (int qf=0; qf<8; ++qf){
    f32x4 il4 = *(const f32x4*)&Linv[qf*16 + g4*4];
#pragma unroll
    for (int df=0; df<4; ++df){
#pragma unroll
      for (int r=0; r<4; ++r){
        int q = qr0 + qf*16 + g4*4 + r;
        int d = nh*DHn + wid*64 + df*16 + ln;
        ctx[((size_t)(b*Sn + q))*Hn + d] = f2bf(o2[qf][df][r]*il4[r]);
      }
    }
  }
}

// ---------------- LN2 in-place on bf16, wave-per-row (no barriers/LDS) ----------------
__global__ __launch_bounds__(256) void ln2_kernel(u16* __restrict__ t, const float* __restrict__ g,
    const float* __restrict__ be){
  int lane = threadIdx.x&63, wid = threadIdx.x>>6;
  int row = blockIdx.x*4 + wid;
  u16* rp = t + (size_t)row*Hn;
  float x[16];
#pragma unroll
  for (int c=0;c<4;++c){
    const ushort4 xu = *(const ushort4*)&rp[lane*4 + c*256];
    x[c*4+0]=bf2f(xu.x); x[c*4+1]=bf2f(xu.y); x[c*4+2]=bf2f(xu.z); x[c*4+3]=bf2f(xu.w);
  }
  float s = 0.f;
#pragma unroll
  for (int e=0;e<16;++e) s += x[e];
#pragma unroll
  for (int m=32;m>=1;m>>=1) s += __shfl_xor(s, m, 64);
  float mean = s*(1.0f/Hn);
  float sq = 0.f;
#pragma unroll
  for (int e=0;e<16;++e){ float d = x[e]-mean; sq += d*d; }
#pragma unroll
  for (int m=32;m>=1;m>>=1) sq += __shfl_xor(sq, m, 64);
  float rstd = rsqrtf(sq*(1.0f/Hn) + 1e-12f);
#pragma unroll
  for (int c=0;c<4;++c){
    int col = lane*4 + c*256;
    ushort4 y;
    y.x = f2bf((x[c*4+0]-mean)*rstd*g[col+0] + be[col+0]);
    y.y = f2bf((x[c*4+1]-mean)*rstd*g[col+1] + be[col+1]);
    y.z = f2bf((x[c*4+2]-mean)*rstd*g[col+2] + be[col+2]);
    y.w = f2bf((x[c*4+3]-mean)*rstd*g[col+3] + be[col+3]);
    *(ushort4*)&rp[col] = y;
  }
}

// ---------------- span mean (bf16 input), 4-wave row-split ----------------
// Each of 4 waves accumulates rows hd+wid, hd+wid+4, ... privately (4x shorter
// serial chain, 4x more loads in flight), then LDS combine + wave-0 write.
__global__ __launch_bounds__(256) void span_kernel(const u16* __restrict__ y, const int* __restrict__ head,
    const int* __restrict__ tail, float* __restrict__ out){
  __shared__ float part[4][256];
  int bs = blockIdx.x;
  int b = bs >> 5;
  int hd = head[bs], tl = tail[bs];
  int lane = threadIdx.x&63, wid = threadIdx.x>>6;
  int c = lane*4;   // wave covers cols [lane*4 .. lane*4+3] of its 256-col quarter? no:
  // each wave covers ALL 1024 cols? 64 lanes x 4 = 256 cols only. Assign wave w cols w*256..+255
  // and ALL rows; but then serial chain unchanged. Instead: all waves cover all 1024 cols is
  // impossible with 64 lanes x 16B. So: wave handles cols (lane*4 + 0..3) in 4 chunks of 256,
  // rows strided by 4 starting at hd+wid.
  float a[16];
#pragma unroll
  for (int e=0;e<16;++e) a[e] = 0.f;
  for (int s=hd+wid; s<tl; s+=4){
    const u16* rp = y + ((size_t)(b*Sn + s))*Hn;
#pragma unroll
    for (int ch=0; ch<4; ++ch){
      const ushort4 v = *(const ushort4*)&rp[c + ch*256];
      a[ch*4+0]+=bf2f(v.x); a[ch*4+1]+=bf2f(v.y); a[ch*4+2]+=bf2f(v.z); a[ch*4+3]+=bf2f(v.w);
    }
  }
  // combine: part[wid][col-within-1024 mapped as lane*4+ch*256 -> store per-wave then sum
#pragma unroll
  for (int ch=0; ch<4; ++ch){
    // pack this wave's 4 floats for chunk ch at columns c..c+3 of chunk ch
    *(float4*)&part[wid][0] = *(float4*)&part[wid][0]; // no-op to keep layout clear
  }
  // store: each wave writes its accumulators to part[wid][...] covering 1024 floats? 256 floats per wave slot
  // Layout: part[wid][lane*4+k] holds chunk-sum for column (ch loop handled below via reuse)
  // Do the combine chunk-by-chunk to fit 256-wide scratch:
  float inv = 1.0f/(float)(tl-hd);
#pragma unroll
  for (int ch=0; ch<4; ++ch){
    *(float4*)&part[wid][lane*4] = (float4){a[ch*4+0],a[ch*4+1],a[ch*4+2],a[ch*4+3]};
    __syncthreads();
    if (wid==0){
      float4 p0 = *(float4*)&part[0][lane*4];
      float4 p1 = *(float4*)&part[1][lane*4];
      float4 p2 = *(float4*)&part[2][lane*4];
      float4 p3 = *(float4*)&part[3][lane*4];
      float4 o;
      o.x = (p0.x+p1.x+p2.x+p3.x)*inv;
      o.y = (p0.y+p1.y+p2.y+p3.y)*inv;
      o.z = (p0.z+p1.z+p2.z+p3.z)*inv;
      o.w = (p0.w+p1.w+p2.w+p3.w)*inv;
      *(float4*)&out[(size_t)bs*Hn + ch*256 + lane*4] = o;
    }
    __syncthreads();
  }
}

extern "C" void kernel_launch(void* const* d_in, const int* in_sizes, int n_in,
                              void* d_out, int out_size, void* d_ws, size_t ws_size,
                              hipStream_t stream) {
  const float* hs    = (const float*)d_in[0];
  const int*   mask  = (const int*)d_in[1];
  const int*   shead = (const int*)d_in[2];
  const int*   stail = (const int*)d_in[3];
  const float* lw    = (const float*)d_in[4];
  const float* ln1g  = (const float*)d_in[5];
  const float* ln1b  = (const float*)d_in[6];
  const float* Wq    = (const float*)d_in[7];
  const float* bq    = (const float*)d_in[8];
  const float* Wk    = (const float*)d_in[9];
  const float* bk    = (const float*)d_in[10];
  const float* Wv    = (const float*)d_in[11];
  const float* bv    = (const float*)d_in[12];
  const float* Wo    = (const float*)d_in[13];
  const float* bo    = (const float*)d_in[14];
  const float* ln2g  = (const float*)d_in[15];
  const float* ln2b  = (const float*)d_in[16];

  char* ws = (char*)d_ws;
  u16* xb  = (u16*)(ws);                 // 32 MiB
  u16* wb  = (u16*)(ws + 33554432);      // 8 MiB (Wq,Wk,Wv,Wo bf16)
  u16* qb  = (u16*)(ws + 41943040);      // 32 MiB
  u16* kb  = (u16*)(ws + 75497472);      // 32 MiB
  u16* vt  = (u16*)(ws + 109051904);     // 32 MiB
  u16* ctx = (u16*)(ws + 142606336);     // 32 MiB ; ends at 176160768
  u16* t   = (u16*)(ws + 41943040);      // 32 MiB bf16, overlays qb (dead after attn)
  float* out = (float*)d_out;

  convw_kernel<<<dim3(1024,4),256,0,stream>>>(Wq,Wk,Wv,Wo,wb);
  mixln_kernel<<<Mn,256,0,stream>>>(hs,lw,ln1g,ln1b,xb);
  gemm256_kernel<0><<<256,512,0,stream>>>(xb, wb,           bq, nullptr, qb, 0.044194173824159223f);
  gemm256_kernel<0><<<256,512,0,stream>>>(xb, wb+1048576,   bk, nullptr, kb, 1.0f);
  gemm256_kernel<1><<<256,512,0,stream>>>(xb, wb+2097152,   bv, nullptr, vt, 1.0f);
  attn_kernel<<<256,512,0,stream>>>(qb,kb,vt,mask,ctx);
  gemm256_kernel<2><<<256,512,0,stream>>>(ctx, wb+3145728,  bo, xb, t, 1.0f);
  ln2_kernel<<<Mn/4,256,0,stream>>>(t, ln2g, ln2b);
  span_kernel<<<Bn*NSn,256,0,stream>>>(t, shead, stail, out);
}

// Round 17
// 452.811 us; speedup vs baseline: 1.7175x; 1.0265x over previous
//
#include <hip/hip_runtime.h>
#include <stdint.h>

#define Ln 4
#define Bn 8
#define Sn 2048
#define Hn 1024
#define NHn 2
#define DHn 512
#define NSn 32
#define Mn (Bn*Sn)

typedef __attribute__((ext_vector_type(8))) short bf16x8;
typedef __attribute__((ext_vector_type(4))) float f32x4;
typedef unsigned short u16;

__device__ __forceinline__ float bf2f(u16 u){
  union { unsigned int i; float f; } c; c.i = ((unsigned int)u)<<16; return c.f;
}
__device__ __forceinline__ u16 f2bf(float f){
  union { float f; unsigned int i; } c; c.f = f;
  unsigned int r = c.i + 0x7FFFu + ((c.i>>16)&1u);
  return (u16)(r>>16);
}
__device__ __forceinline__ uint32_t packbf(float a, float b){
  return (uint32_t)f2bf(a) | ((uint32_t)f2bf(b)<<16);
}
__device__ __forceinline__ void gl2lds16(const void* g, void* l){
  __builtin_amdgcn_global_load_lds((const __attribute__((address_space(1))) void*)g,
                                   (__attribute__((address_space(3))) void*)l, 16, 0, 0);
}

__device__ __forceinline__ float block_sum256(float v, float* red){
#pragma unroll
  for (int m=32;m>=1;m>>=1) v += __shfl_xor(v, m, 64);
  int tid = threadIdx.x;
  if ((tid&63)==0) red[tid>>6] = v;
  __syncthreads();
  v = red[0]+red[1]+red[2]+red[3];
  __syncthreads();
  return v;
}

// ---------------- weight f32 -> bf16 ----------------
__global__ __launch_bounds__(256) void convw_kernel(const float* __restrict__ Wq, const float* __restrict__ Wk,
    const float* __restrict__ Wv, const float* __restrict__ Wo, u16* __restrict__ wb){
  int m = blockIdx.y;
  const float* src = (m==0)?Wq:(m==1)?Wk:(m==2)?Wv:Wo;
  size_t i = ((size_t)blockIdx.x*256 + threadIdx.x)*4;
  const float4 v = *(const float4*)&src[i];
  ushort4 o;
  o.x=f2bf(v.x); o.y=f2bf(v.y); o.z=f2bf(v.z); o.w=f2bf(v.w);
  *(ushort4*)&wb[(size_t)m*Hn*Hn + i] = o;
}

// ---------------- layer mix + LN1 -> x (bf16) ----------------
__global__ __launch_bounds__(256) void mixln_kernel(const float* __restrict__ hs, const float* __restrict__ lw,
    const float* __restrict__ g, const float* __restrict__ be, u16* __restrict__ xb){
  __shared__ float red[4];
  int row = blockIdx.x;
  int tid = threadIdx.x;
  float l0=lw[0], l1=lw[1], l2=lw[2], l3=lw[3];
  float mx = fmaxf(fmaxf(l0,l1),fmaxf(l2,l3));
  float e0=__expf(l0-mx), e1=__expf(l1-mx), e2=__expf(l2-mx), e3=__expf(l3-mx);
  float inv = 1.0f/(e0+e1+e2+e3);
  e0*=inv; e1*=inv; e2*=inv; e3*=inv;
  size_t base = (size_t)row*Hn + tid*4;
  const float4 h0 = *(const float4*)&hs[base];
  const float4 h1 = *(const float4*)&hs[base + (size_t)Mn*Hn];
  const float4 h2 = *(const float4*)&hs[base + (size_t)2*Mn*Hn];
  const float4 h3 = *(const float4*)&hs[base + (size_t)3*Mn*Hn];
  float x0 = e0*h0.x + e1*h1.x + e2*h2.x + e3*h3.x;
  float x1 = e0*h0.y + e1*h1.y + e2*h2.y + e3*h3.y;
  float x2 = e0*h0.z + e1*h1.z + e2*h2.z + e3*h3.z;
  float x3 = e0*h0.w + e1*h1.w + e2*h2.w + e3*h3.w;
  float s = block_sum256(x0+x1+x2+x3, red);
  float mean = s * (1.0f/Hn);
  float d0=x0-mean, d1=x1-mean, d2=x2-mean, d3=x3-mean;
  float sq = block_sum256(d0*d0+d1*d1+d2*d2+d3*d3, red);
  float rstd = rsqrtf(sq*(1.0f/Hn) + 1e-7f);
  int c = tid*4;
  ushort4 o;
  o.x = f2bf(d0*rstd*g[c+0] + be[c+0]);
  o.y = f2bf(d1*rstd*g[c+1] + be[c+1]);
  o.z = f2bf(d2*rstd*g[c+2] + be[c+2]);
  o.w = f2bf(d3*rstd*g[c+3] + be[c+3]);
  *(ushort4*)&xb[(size_t)row*Hn + c] = o;
}

// ---------------- GEMM 256x256, BK=64x2 per iter, 8-phase counted-vmcnt (validated) ----------------
template<int MODE>
__global__ __launch_bounds__(512,2) void gemm256_kernel(const u16* __restrict__ A, const u16* __restrict__ Bw,
    const float* __restrict__ bias, const u16* __restrict__ resid, void* __restrict__ Cout, float scale){
  __shared__ char ldsb[131072];   // [buf][A/B][half][128x64 bf16 = 16KB]
  int tid = threadIdx.x, lane = tid&63, wid = tid>>6;
  int ln = lane&15, g4 = lane>>4;
  int wm = wid>>2, wn = wid&3;        // wave grid 2M x 4N; per-wave out 128x64
  int swz = (blockIdx.x&7)*32 + (blockIdx.x>>3);
  int i0 = (swz>>2)*256;
  int j0 = (swz&3)*256;

  f32x4 acc[8][4];
#pragma unroll
  for (int a=0;a<8;a++)
#pragma unroll
    for (int b=0;b<4;b++) acc[a][b] = (f32x4){0.f,0.f,0.f,0.f};

  const u16* Asrc = A + (size_t)i0*Hn;
  const u16* Bsrc = Bw + (size_t)j0*Hn;
  const int hA = wm, hB = wn>>1, bB = (wn&1)*64;

#define LDSOFF(B,AB,H) ((((B)*2+(AB))*2+(H))*16384)
#define STG(AB,H,B,T) do { \
    const u16* s_ = (AB) ? Bsrc : Asrc; \
    char* d_ = ldsb + LDSOFF(B,AB,H); \
    _Pragma("unroll") \
    for (int l_=0;l_<2;++l_){ \
      int g_ = l_*512 + tid; int r_ = g_>>3; int cs_ = (g_&7) ^ (r_&7); \
      gl2lds16(s_ + (size_t)((H)*128 + r_)*Hn + (T)*64 + cs_*8, d_ + g_*16); \
    } } while(0)
#define RDH(B,AB,H,RR,KG) (*(const bf16x8*)(ldsb + LDSOFF(B,AB,H) + (RR)*128 + ((((KG)) ^ ((RR)&7))<<4)))
#define LOADA(B,I) { _Pragma("unroll") for (int mt=0;mt<4;++mt) \
    _Pragma("unroll") for (int kk=0;kk<2;++kk) af[mt][kk] = RDH(B,0,hA,(I)*64+mt*16+ln, kk*4+g4); }
#define LOADB(B,ARR,J) { _Pragma("unroll") for (int nt=0;nt<2;++nt) \
    _Pragma("unroll") for (int kk=0;kk<2;++kk) ARR[nt][kk] = RDH(B,1,hB, bB+((J)*2+nt)*16+ln, kk*4+g4); }
#define PH_OPEN __builtin_amdgcn_s_barrier(); \
    asm volatile("s_waitcnt lgkmcnt(0)" ::: "memory"); \
    __builtin_amdgcn_sched_barrier(0);
#define MM(I,J,BF) { __builtin_amdgcn_s_setprio(1); \
    _Pragma("unroll") for (int kk=0;kk<2;++kk) \
    _Pragma("unroll") for (int mt=0;mt<4;++mt) \
    _Pragma("unroll") for (int nt=0;nt<2;++nt) \
      acc[(I)*4+mt][(J)*2+nt] = __builtin_amdgcn_mfma_f32_16x16x32_bf16(af[mt][kk], BF[nt][kk], acc[(I)*4+mt][(J)*2+nt], 0,0,0); \
    __builtin_amdgcn_s_setprio(0); }
#define PH_CLOSE __builtin_amdgcn_s_barrier();

  STG(0,0,0,0); STG(0,1,0,0); STG(1,0,0,0); STG(1,1,0,0);
  STG(0,0,1,1);
  asm volatile("s_waitcnt vmcnt(2)" ::: "memory");
  __builtin_amdgcn_s_barrier();

  bf16x8 af[4][2], bf0[2][2], bf1[2][2];
#pragma unroll 1
  for (int it=0; it<8; ++it){
    const int u = 2*it, v = 2*it+1;
    const bool st = (it < 7);
    LOADA(0,0); LOADB(0,bf0,0);
    STG(0,1,1,v);
    PH_OPEN; MM(0,0,bf0); PH_CLOSE;
    LOADB(0,bf1,1);
    STG(1,0,1,v);
    PH_OPEN; MM(0,1,bf1); PH_CLOSE;
    LOADA(0,1);
    STG(1,1,1,v);
    PH_OPEN; MM(1,0,bf0); PH_CLOSE;
    if (st) STG(0,0,0,u+2);
    PH_OPEN; MM(1,1,bf1);
    if (st) { asm volatile("s_waitcnt vmcnt(2)" ::: "memory"); }
    else    { asm volatile("s_waitcnt vmcnt(0)" ::: "memory"); }
    PH_CLOSE;
    LOADA(1,0); LOADB(1,bf0,0);
    if (st) STG(0,1,0,u+2);
    PH_OPEN; MM(0,0,bf0); PH_CLOSE;
    LOADB(1,bf1,1);
    if (st) STG(1,0,0,u+2);
    PH_OPEN; MM(0,1,bf1); PH_CLOSE;
    LOADA(1,1);
    if (st) STG(1,1,0,u+2);
    PH_OPEN; MM(1,0,bf0); PH_CLOSE;
    if (st) STG(0,0,1,v+2);
    PH_OPEN; MM(1,1,bf1);
    if (st) { asm volatile("s_waitcnt vmcnt(2)" ::: "memory"); }
    else    { asm volatile("s_waitcnt vmcnt(0)" ::: "memory"); }
    PH_CLOSE;
  }
#undef LDSOFF
#undef STG
#undef RDH
#undef LOADA
#undef LOADB
#undef PH_OPEN
#undef MM
#undef PH_CLOSE

#pragma unroll
  for (int mt=0; mt<8; ++mt){
#pragma unroll
    for (int nt=0; nt<4; ++nt){
#pragma unroll
      for (int r=0; r<4; ++r){
        int i = i0 + wm*128 + mt*16 + g4*4 + r;
        int j = j0 + wn*64 + nt*16 + ln;
        float v = acc[mt][nt][r] + bias[j];
        if (MODE==0){
          int b = i>>11, s = i&2047, nh = j>>9, dh = j&511;
          ((u16*)Cout)[(((size_t)(b*NHn+nh)*Sn + s)<<9) + dh] = f2bf(v*scale);
        } else if (MODE==1){
          int b = i>>11, s = i&2047, nh = j>>9, dh = j&511;
          ((u16*)Cout)[((size_t)((b*NHn+nh)*(Sn/32) + (s>>5))<<14) + (dh<<5) + (s&31)] = f2bf(v);
        } else {
          float res = bf2f(resid[(size_t)i*Hn + j]);
          ((u16*)Cout)[(size_t)i*Hn + j] = f2bf(v + res);
        }
      }
    }
  }
}

// ---------------- flash attention (R10 structure — best measured: ~227us) ----------------
__global__ __launch_bounds__(512,2) void attn_kernel(const u16* __restrict__ qb, const u16* __restrict__ kb,
    const u16* __restrict__ vt, const int* __restrict__ mask, u16* __restrict__ ctx){
  __shared__ u16 Ks[2][32*512];  // 2x32KB, row-swizzled
  __shared__ u16 Vs[2][512*32];  // 2x32KB, tiled V^T (d, k%32), granule-swizzled
  __shared__ u16 Ps[8*16*32];    // block-shared P[128q][32k], wave-region + granule-swizzled
  __shared__ float Lcorr[128];   // per-q rescale factor (1.0 if none)
  __shared__ float Lflag[8];     // per-wave rescale flag
  __shared__ float Linv[128];    // per-q 1/l (epilogue)
  int tid = threadIdx.x, lane = tid&63, wid = tid>>6;
  int ln = lane&15, g4 = lane>>4;
  int gid = blockIdx.x;
  int xcd = gid&7, ord = gid>>3;
  int bh = xcd*2 + (ord>>4), qt = ord&15;   // 16 qt-blocks of one bh share an XCD
  int b = bh >> 1, nh = bh & 1;
  u16* pw = Ps + wid*512;
  uint32_t* pw32 = (uint32_t*)pw;
  const int swz = (ln&7)<<4;
  const int rsw = (ln>>1)&3;     // P/V swizzle key

  bf16x8 aq[16];
  size_t qoff = ((size_t)bh*Sn + qt*128 + wid*16 + ln)*DHn + g4*8;
#pragma unroll
  for (int ch=0; ch<16; ++ch) aq[ch] = *(const bf16x8*)&qb[qoff + ch*32];

  // o2[qf][df]: q = qf*16 + g4*4 + r ; d = wid*64 + df*16 + ln
  f32x4 o2[8][4];
#pragma unroll
  for (int qf=0; qf<8; ++qf)
#pragma unroll
    for (int df=0; df<4; ++df) o2[qf][df] = (f32x4){0.f,0.f,0.f,0.f};
  float mrun = -1e30f, lrun = 0.f;

  const size_t kbase = (size_t)bh*Sn*DHn;
  const u16* vtile = vt + (size_t)bh*Sn*DHn;   // tiled V^T: [kt][512 d][32 k]

#define STAGE_KV(KT,BUF) do { \
  _Pragma("unroll") \
  for (int t_=0; t_<4; ++t_){ \
    int krow_ = t_*8 + wid; \
    int koff_ = (lane*16) ^ ((krow_&7)<<4); \
    gl2lds16(&kb[kbase + ((size_t)((KT)*32 + krow_))*DHn + (koff_>>1)], \
             (char*)Ks[BUF] + krow_*1024 + lane*16); \
  } \
  _Pragma("unroll") \
  for (int t_=0; t_<4; ++t_){ \
    int p_ = t_*512 + tid; \
    int cgd_ = ((p_&3) ^ ((p_>>3)&3)); \
    gl2lds16(&vtile[(size_t)(KT)*16384 + (p_&~3)*8 + cgd_*8], \
             (char*)Vs[BUF] + p_*16); \
  } } while(0)

  STAGE_KV(0,0);
  __syncthreads();   // tile 0 resident
#pragma unroll 1
  for (int kt=0; kt<Sn/32; ++kt){
    int cur = kt&1;
    if (kt < Sn/32 - 1) STAGE_KV(kt+1, cur^1);   // DMA spans the raw barrier; drained at end sync
    const char* KsB = (const char*)Ks[cur];
    f32x4 s0 = (f32x4){0.f,0.f,0.f,0.f};
    f32x4 s1 = (f32x4){0.f,0.f,0.f,0.f};
#pragma unroll
    for (int ch=0; ch<16; ++ch){
      bf16x8 k0 = *(const bf16x8*)(KsB + ln*1024      + ((ch*64 + g4*16) ^ swz));
      bf16x8 k1 = *(const bf16x8*)(KsB + (16+ln)*1024 + ((ch*64 + g4*16) ^ swz));
      s0 = __builtin_amdgcn_mfma_f32_16x16x32_bf16(k0, aq[ch], s0, 0,0,0);
      s1 = __builtin_amdgcn_mfma_f32_16x16x32_bf16(k1, aq[ch], s1, 0,0,0);
    }
    int4 mk0 = *(const int4*)&mask[b*Sn + kt*32 + g4*4];
    int4 mk1 = *(const int4*)&mask[b*Sn + kt*32 + 16 + g4*4];
    s0[0] += (float)(1-mk0.x)*-10000.0f; s0[1] += (float)(1-mk0.y)*-10000.0f;
    s0[2] += (float)(1-mk0.z)*-10000.0f; s0[3] += (float)(1-mk0.w)*-10000.0f;
    s1[0] += (float)(1-mk1.x)*-10000.0f; s1[1] += (float)(1-mk1.y)*-10000.0f;
    s1[2] += (float)(1-mk1.z)*-10000.0f; s1[3] += (float)(1-mk1.w)*-10000.0f;
    float tmax = fmaxf(fmaxf(fmaxf(s0[0],s0[1]),fmaxf(s0[2],s0[3])),
                       fmaxf(fmaxf(s1[0],s1[1]),fmaxf(s1[2],s1[3])));
    tmax = fmaxf(tmax, __shfl_xor(tmax, 16));
    tmax = fmaxf(tmax, __shfl_xor(tmax, 32));
    float corr = 1.0f, wflag = 0.0f;
    if (__any(tmax > mrun + 8.0f)){     // defer-max: rare rescale
      float nm = fmaxf(mrun, tmax);
      corr = __expf(mrun - nm);
      mrun = nm; lrun *= corr;
      wflag = 1.0f;
    }
    float p0=__expf(s0[0]-mrun), p1=__expf(s0[1]-mrun), p2=__expf(s0[2]-mrun), p3=__expf(s0[3]-mrun);
    float p4=__expf(s1[0]-mrun), p5=__expf(s1[1]-mrun), p6=__expf(s1[2]-mrun), p7=__expf(s1[3]-mrun);
    float sum = ((p0+p1)+(p2+p3)) + ((p4+p5)+(p6+p7));
    sum += __shfl_xor(sum, 16);
    sum += __shfl_xor(sum, 32);
    lrun += sum;
    // P write: swizzled granules — granule (q,gr) at u16 q*32 + (gr^((q>>1)&3))*8.
    {
      int base = ln*16 + ((g4&1)<<1);
      pw32[base + (((g4>>1)    ^rsw)<<2)    ] = packbf(p0,p1);
      pw32[base + (((g4>>1)    ^rsw)<<2) + 1] = packbf(p2,p3);
      pw32[base + ((((g4>>1)+2)^rsw)<<2)    ] = packbf(p4,p5);
      pw32[base + ((((g4>>1)+2)^rsw)<<2) + 1] = packbf(p6,p7);
    }
    if (lane < 16) Lcorr[wid*16 + ln] = corr;
    if (lane == 0) Lflag[wid] = wflag;
    // ---- mid-iter barrier: DS visibility only; staging DMA stays in flight
    __builtin_amdgcn_sched_barrier(0);
    asm volatile("s_waitcnt lgkmcnt(0)" ::: "memory");
    __builtin_amdgcn_s_barrier();
    __builtin_amdgcn_sched_barrier(0);
    // ---- cross-wave rescale (rare)
    {
      f32x4 fl0 = *(const f32x4*)&Lflag[0];
      f32x4 fl1 = *(const f32x4*)&Lflag[4];
      float fs = (fl0[0]+fl0[1]+fl0[2]+fl0[3]) + (fl1[0]+fl1[1]+fl1[2]+fl1[3]);
      if (fs > 0.5f){
#pragma unroll
        for (int qf=0; qf<8; ++qf){
          f32x4 c4 = *(const f32x4*)&Lcorr[qf*16 + g4*4];
#pragma unroll
          for (int df=0; df<4; ++df){
            o2[qf][df][0]*=c4[0]; o2[qf][df][1]*=c4[1];
            o2[qf][df][2]*=c4[2]; o2[qf][df][3]*=c4[3];
          }
        }
      }
    }
    // ---- PV: wave computes all 128 q for its 64-wide d-slice
    const char* VsB = (const char*)Vs[cur];
    bf16x8 bv[4];
#pragma unroll
    for (int df=0; df<4; ++df)
      bv[df] = *(const bf16x8*)(VsB + ((wid*4+df)*16+ln)*64 + ((g4 ^ rsw)<<4));
#pragma unroll
    for (int qf=0; qf<8; ++qf){
      bf16x8 aP = *(const bf16x8*)&Ps[qf*512 + ln*32 + ((g4 ^ rsw)<<3)];
#pragma unroll
      for (int df=0; df<4; ++df)
        o2[qf][df] = __builtin_amdgcn_mfma_f32_16x16x32_bf16(aP, bv[df], o2[qf][df], 0,0,0);
    }
    __syncthreads();   // drains vmcnt(0): tile kt+1 landed; all reads of cur done
  }
#undef STAGE_KV
  if (lane < 16) Linv[wid*16 + ln] = 1.0f/lrun;
  __syncthreads();
  int qr0 = qt*128;
#pragma unroll
  for (int qf=0; qf<8; ++qf){
    f32x4 il4 = *(const f32x4*)&Linv[qf*16 + g4*4];
#pragma unroll
    for (int df=0; df<4; ++df){
#pragma unroll
      for (int r=0; r<4; ++r){
        int q = qr0 + qf*16 + g4*4 + r;
        int d = nh*DHn + wid*64 + df*16 + ln;
        ctx[((size_t)(b*Sn + q))*Hn + d] = f2bf(o2[qf][df][r]*il4[r]);
      }
    }
  }
}

// ---------------- LN2 in-place on bf16, wave-per-row (no barriers/LDS) ----------------
__global__ __launch_bounds__(256) void ln2_kernel(u16* __restrict__ t, const float* __restrict__ g,
    const float* __restrict__ be){
  int lane = threadIdx.x&63, wid = threadIdx.x>>6;
  int row = blockIdx.x*4 + wid;
  u16* rp = t + (size_t)row*Hn;
  float x[16];
#pragma unroll
  for (int c=0;c<4;++c){
    const ushort4 xu = *(const ushort4*)&rp[lane*4 + c*256];
    x[c*4+0]=bf2f(xu.x); x[c*4+1]=bf2f(xu.y); x[c*4+2]=bf2f(xu.z); x[c*4+3]=bf2f(xu.w);
  }
  float s = 0.f;
#pragma unroll
  for (int e=0;e<16;++e) s += x[e];
#pragma unroll
  for (int m=32;m>=1;m>>=1) s += __shfl_xor(s, m, 64);
  float mean = s*(1.0f/Hn);
  float sq = 0.f;
#pragma unroll
  for (int e=0;e<16;++e){ float d = x[e]-mean; sq += d*d; }
#pragma unroll
  for (int m=32;m>=1;m>>=1) sq += __shfl_xor(sq, m, 64);
  float rstd = rsqrtf(sq*(1.0f/Hn) + 1e-12f);
#pragma unroll
  for (int c=0;c<4;++c){
    int col = lane*4 + c*256;
    ushort4 y;
    y.x = f2bf((x[c*4+0]-mean)*rstd*g[col+0] + be[col+0]);
    y.y = f2bf((x[c*4+1]-mean)*rstd*g[col+1] + be[col+1]);
    y.z = f2bf((x[c*4+2]-mean)*rstd*g[col+2] + be[col+2]);
    y.w = f2bf((x[c*4+3]-mean)*rstd*g[col+3] + be[col+3]);
    *(ushort4*)&rp[col] = y;
  }
}

// ---------------- span mean (bf16 input), 8-wave row-split ----------------
// 8 waves accumulate rows hd+wid, hd+wid+8, ... privately (8x shorter serial
// chain), then chunk-by-chunk LDS combine; wave 0 writes.
__global__ __launch_bounds__(512) void span_kernel(const u16* __restrict__ y, const int* __restrict__ head,
    const int* __restrict__ tail, float* __restrict__ out){
  __shared__ float part[8][256];
  int bs = blockIdx.x;
  int b = bs >> 5;
  int hd = head[bs], tl = tail[bs];
  int lane = threadIdx.x&63, wid = threadIdx.x>>6;   // wid 0..7
  int c = lane*4;
  float a[16];
#pragma unroll
  for (int e=0;e<16;++e) a[e] = 0.f;
  for (int s=hd+wid; s<tl; s+=8){
    const u16* rp = y + ((size_t)(b*Sn + s))*Hn;
#pragma unroll
    for (int ch=0; ch<4; ++ch){
      const ushort4 v = *(const ushort4*)&rp[c + ch*256];
      a[ch*4+0]+=bf2f(v.x); a[ch*4+1]+=bf2f(v.y); a[ch*4+2]+=bf2f(v.z); a[ch*4+3]+=bf2f(v.w);
    }
  }
  float inv = 1.0f/(float)(tl-hd);
#pragma unroll
  for (int ch=0; ch<4; ++ch){
    *(float4*)&part[wid][lane*4] = (float4){a[ch*4+0],a[ch*4+1],a[ch*4+2],a[ch*4+3]};
    __syncthreads();
    if (wid==0){
      float4 p0 = *(float4*)&part[0][lane*4];
      float4 p1 = *(float4*)&part[1][lane*4];
      float4 p2 = *(float4*)&part[2][lane*4];
      float4 p3 = *(float4*)&part[3][lane*4];
      float4 p4 = *(float4*)&part[4][lane*4];
      float4 p5 = *(float4*)&part[5][lane*4];
      float4 p6 = *(float4*)&part[6][lane*4];
      float4 p7 = *(float4*)&part[7][lane*4];
      float4 o;
      o.x = ((p0.x+p1.x)+(p2.x+p3.x)+(p4.x+p5.x)+(p6.x+p7.x))*inv;
      o.y = ((p0.y+p1.y)+(p2.y+p3.y)+(p4.y+p5.y)+(p6.y+p7.y))*inv;
      o.z = ((p0.z+p1.z)+(p2.z+p3.z)+(p4.z+p5.z)+(p6.z+p7.z))*inv;
      o.w = ((p0.w+p1.w)+(p2.w+p3.w)+(p4.w+p5.w)+(p6.w+p7.w))*inv;
      *(float4*)&out[(size_t)bs*Hn + ch*256 + lane*4] = o;
    }
    __syncthreads();
  }
}

extern "C" void kernel_launch(void* const* d_in, const int* in_sizes, int n_in,
                              void* d_out, int out_size, void* d_ws, size_t ws_size,
                              hipStream_t stream) {
  const float* hs    = (const float*)d_in[0];
  const int*   mask  = (const int*)d_in[1];
  const int*   shead = (const int*)d_in[2];
  const int*   stail = (const int*)d_in[3];
  const float* lw    = (const float*)d_in[4];
  const float* ln1g  = (const float*)d_in[5];
  const float* ln1b  = (const float*)d_in[6];
  const float* Wq    = (const float*)d_in[7];
  const float* bq    = (const float*)d_in[8];
  const float* Wk    = (const float*)d_in[9];
  const float* bk    = (const float*)d_in[10];
  const float* Wv    = (const float*)d_in[11];
  const float* bv    = (const float*)d_in[12];
  const float* Wo    = (const float*)d_in[13];
  const float* bo    = (const float*)d_in[14];
  const float* ln2g  = (const float*)d_in[15];
  const float* ln2b  = (const float*)d_in[16];

  char* ws = (char*)d_ws;
  u16* xb  = (u16*)(ws);                 // 32 MiB
  u16* wb  = (u16*)(ws + 33554432);      // 8 MiB (Wq,Wk,Wv,Wo bf16)
  u16* qb  = (u16*)(ws + 41943040);      // 32 MiB
  u16* kb  = (u16*)(ws + 75497472);      // 32 MiB
  u16* vt  = (u16*)(ws + 109051904);     // 32 MiB
  u16* ctx = (u16*)(ws + 142606336);     // 32 MiB ; ends at 176160768
  u16* t   = (u16*)(ws + 41943040);      // 32 MiB bf16, overlays qb (dead after attn)
  float* out = (float*)d_out;

  convw_kernel<<<dim3(1024,4),256,0,stream>>>(Wq,Wk,Wv,Wo,wb);
  mixln_kernel<<<Mn,256,0,stream>>>(hs,lw,ln1g,ln1b,xb);
  gemm256_kernel<0><<<256,512,0,stream>>>(xb, wb,           bq, nullptr, qb, 0.044194173824159223f);
  gemm256_kernel<0><<<256,512,0,stream>>>(xb, wb+1048576,   bk, nullptr, kb, 1.0f);
  gemm256_kernel<1><<<256,512,0,stream>>>(xb, wb+2097152,   bv, nullptr, vt, 1.0f);
  attn_kernel<<<256,512,0,stream>>>(qb,kb,vt,mask,ctx);
  gemm256_kernel<2><<<256,512,0,stream>>>(ctx, wb+3145728,  bo, xb, t, 1.0f);
  ln2_kernel<<<Mn/4,256,0,stream>>>(t, ln2g, ln2b);
  span_kernel<<<Bn*NSn,512,0,stream>>>(t, shead, stail, out);
}